// Round 9
// baseline (459.400 us; speedup 1.0000x reference)
//
#include <hip/hip_runtime.h>
#include <math.h>

#define BATCH 8
#define SSIZE 1048576   // 128*128*64

// R15: software pipeline (depth-2 register prefetch) on all 4 tiled kernels.
// R8 counters: gram 46.2us, no pipe >30%, ~14K cyc/k-step vs ~2K issued work
// => serial HBM latency per k-step. Prefetch next k-step's global loads into
// regs between the barriers (under ds_read+MFMA). VGPR 56->~90, LDS-capped
// occupancy unchanged. Old session's anti-prefetch rule was for VGPR-40
// fp32 kernels on an occupancy cliff -- mechanism absent here.
// score/reduce unchanged (R14 measured 422.0us, absmax 3.05e-5).

typedef short sh8 __attribute__((ext_vector_type(8)));
typedef float f32x4 __attribute__((ext_vector_type(4)));

#define MFMA16(a, b, c) __builtin_amdgcn_mfma_f32_16x16x32_bf16((a), (b), (c), 0, 0, 0)

__device__ __forceinline__ unsigned short bf_rne(float x) {
    unsigned u = __float_as_uint(x);
    unsigned r = u + 0x7fffu + ((u >> 16) & 1u);
    return (unsigned short)(r >> 16);
}

// split x into hi + lo bf16 (both RNE)
__device__ __forceinline__ void split1(float x, unsigned short &h, unsigned short &l) {
    h = bf_rne(x);
    float hf = __uint_as_float((unsigned)h << 16);
    l = bf_rne(x - hf);
}

// split two floats, pack hi pair / lo pair as u32 (a in low 16, b in high)
__device__ __forceinline__ void split2(float a, float b, unsigned &hh, unsigned &ll) {
    unsigned short ha = bf_rne(a), hb = bf_rne(b);
    hh = (unsigned)ha | ((unsigned)hb << 16);
    float ra = a - __uint_as_float((unsigned)ha << 16);
    float rb = b - __uint_as_float((unsigned)hb << 16);
    ll = (unsigned)bf_rne(ra) | ((unsigned)bf_rne(rb) << 16);
}

__device__ __forceinline__ float f4c(const float4 &v, int c) {
    return c == 0 ? v.x : c == 1 ? v.y : c == 2 ? v.z : v.w;
}

// fragment load, pitch-32 planes with XOR swizzle (gram kernels, proven)
__device__ __forceinline__ sh8 ldfrag(const unsigned short *pl, int row, int kg) {
    const int idx = (row * 32 + kg * 8) ^ ((row & 3) << 3);
    return *(const sh8 *)(pl + idx);
}

// fragment load, pitch-40 planes, no swizzle (mix kernels; bank-optimal)
__device__ __forceinline__ sh8 ldfrag40(const unsigned short *pl, int row, int kg) {
    return *(const sh8 *)(pl + row * 40 + kg * 8);
}

// ---------------- partial-slab reduce: out[b][r] = sum_s in[b][s][r] --------
template<int NS, int PERB>   // PERB in float4 units
__global__ __launch_bounds__(256)
void reduce_kernel(const float4* __restrict__ in, float4* __restrict__ out) {
    const int gid = blockIdx.x * blockDim.x + threadIdx.x;
    const int b = gid / PERB, r = gid - b * PERB;
    const float4* p = in + (size_t)b * NS * PERB + r;
    float4 a = p[0];
    #pragma unroll 8
    for (int s = 1; s < NS; s++) {
        const float4 v = p[(size_t)s * PERB];
        a.x += v.x; a.y += v.y; a.z += v.z; a.w += v.w;
    }
    out[gid] = a;
}

// =====================================================================
// gram_mfma (modes 0/1, d=128): G = u u^T, symmetric. R15: reg prefetch.
// =====================================================================
template<int SI_, int KL2_, int SKH_>
__global__ __launch_bounds__(256, 3)
void gram_mfma_kernel(const float* __restrict__ srcR, const float* __restrict__ srcI,
                      float* __restrict__ Gp, int kPerBlock)
{
    const int tile = blockIdx.x;             // 0,1,2
    const int it = (tile == 2) ? 64 : 0;
    const int jt = (tile == 0) ? 0 : 64;
    const bool diag = (it == jt);
    const int b  = blockIdx.z;
    const int k0 = blockIdx.y * kPerBlock;

    const int t    = threadIdx.x;
    const int lane = t & 63;
    const int wave = t >> 6;          // 0..3
    const int wr = wave & 1, wc = wave >> 1;

    __shared__ unsigned short SA[4][2048];   // planes rH,rL,iH,iL  [64 rows][32 k]
    __shared__ unsigned short SB[4][2048];

    const sh8 SGN = {(short)0x8000, (short)0x8000, (short)0x8000, (short)0x8000,
                     (short)0x8000, (short)0x8000, (short)0x8000, (short)0x8000};

    f32x4 gr[2][2], gi[2][2];
    const f32x4 z4 = {0.f, 0.f, 0.f, 0.f};
    #pragma unroll
    for (int x = 0; x < 2; x++)
        #pragma unroll
        for (int y = 0; y < 2; y++) { gr[x][y] = z4; gi[x][y] = z4; }

    const size_t boff = (size_t)b * SSIZE;
    const int nT = kPerBlock >> 5;

    const int kq   = t & 7;
    const int row2 = t >> 3;

    const int frow = lane & 15;
    const int kg   = lane >> 4;

    #define GADDR(ii, k) (boff + (size_t)(ii) * SI_ + \
        (size_t)((k) >> KL2_) * SKH_ + (size_t)((k) & ((1 << KL2_) - 1)))

    float4 pAR[2], pAI[2], pBR[2], pBI[2];
    auto loadk = [&](int kb) {
        #pragma unroll
        for (int m = 0; m < 2; m++) {
            const int row = row2 + 32 * m;
            const size_t offA = GADDR(it + row, kb + kq * 4);
            pAR[m] = *(const float4*)(srcR + offA);
            pAI[m] = *(const float4*)(srcI + offA);
            if (!diag) {
                const size_t offB = GADDR(jt + row, kb + kq * 4);
                pBR[m] = *(const float4*)(srcR + offB);
                pBI[m] = *(const float4*)(srcI + offB);
            }
        }
    };

    loadk(k0);
    for (int kt = 0; kt < nT; kt++) {
        #pragma unroll
        for (int m = 0; m < 2; m++) {
            const int row = row2 + 32 * m;
            const int idx = (row * 32 + kq * 4) ^ ((row & 3) << 3);
            {
                ushort4 rh, rl, ih, il;
                split1(pAR[m].x, rh.x, rl.x); split1(pAR[m].y, rh.y, rl.y);
                split1(pAR[m].z, rh.z, rl.z); split1(pAR[m].w, rh.w, rl.w);
                split1(pAI[m].x, ih.x, il.x); split1(pAI[m].y, ih.y, il.y);
                split1(pAI[m].z, ih.z, il.z); split1(pAI[m].w, ih.w, il.w);
                *(ushort4*)&SA[0][idx] = rh;
                *(ushort4*)&SA[1][idx] = rl;
                *(ushort4*)&SA[2][idx] = ih;
                *(ushort4*)&SA[3][idx] = il;
            }
            if (!diag) {
                ushort4 rh, rl, ih, il;
                split1(pBR[m].x, rh.x, rl.x); split1(pBR[m].y, rh.y, rl.y);
                split1(pBR[m].z, rh.z, rl.z); split1(pBR[m].w, rh.w, rl.w);
                split1(pBI[m].x, ih.x, il.x); split1(pBI[m].y, ih.y, il.y);
                split1(pBI[m].z, ih.z, il.z); split1(pBI[m].w, ih.w, il.w);
                *(ushort4*)&SB[0][idx] = rh;
                *(ushort4*)&SB[1][idx] = rl;
                *(ushort4*)&SB[2][idx] = ih;
                *(ushort4*)&SB[3][idx] = il;
            }
        }
        __syncthreads();

        // prefetch next k-step (issues under ds_read+MFMA below)
        if (kt + 1 < nT) loadk(k0 + (kt + 1) * 32);

        unsigned short (*BP)[2048] = diag ? SA : SB;

        sh8 a[2][4], na[2][2], bfr[2][4];
        #pragma unroll
        for (int s = 0; s < 2; s++) {
            const int row = wr * 32 + s * 16 + frow;
            #pragma unroll
            for (int p = 0; p < 4; p++) a[s][p] = ldfrag(&SA[p][0], row, kg);
            na[s][0] = a[s][2] ^ SGN;
            na[s][1] = a[s][3] ^ SGN;
        }
        #pragma unroll
        for (int s = 0; s < 2; s++) {
            const int row = wc * 32 + s * 16 + frow;
            #pragma unroll
            for (int p = 0; p < 4; p++) bfr[s][p] = ldfrag(&BP[p][0], row, kg);
        }

        #pragma unroll
        for (int sr = 0; sr < 2; sr++) {
            #pragma unroll
            for (int sc = 0; sc < 2; sc++) {
                f32x4 r = gr[sr][sc], q = gi[sr][sc];
                r = MFMA16(a[sr][0],  bfr[sc][0], r);
                r = MFMA16(a[sr][0],  bfr[sc][1], r);
                r = MFMA16(a[sr][1],  bfr[sc][0], r);
                r = MFMA16(na[sr][0], bfr[sc][2], r);
                r = MFMA16(na[sr][0], bfr[sc][3], r);
                r = MFMA16(na[sr][1], bfr[sc][2], r);
                q = MFMA16(a[sr][0],  bfr[sc][2], q);
                q = MFMA16(a[sr][0],  bfr[sc][3], q);
                q = MFMA16(a[sr][1],  bfr[sc][2], q);
                q = MFMA16(a[sr][2],  bfr[sc][0], q);
                q = MFMA16(a[sr][2],  bfr[sc][1], q);
                q = MFMA16(a[sr][3],  bfr[sc][0], q);
                gr[sr][sc] = r; gi[sr][sc] = q;
            }
        }
        __syncthreads();
    }
    #undef GADDR

    float* Gb = Gp + ((size_t)b * gridDim.y + blockIdx.y) * (128 * 128 * 2);
    const int rb   = (lane >> 4) * 4;
    const int jcol = lane & 15;
    #pragma unroll
    for (int sr = 0; sr < 2; sr++)
        #pragma unroll
        for (int sc = 0; sc < 2; sc++)
            #pragma unroll
            for (int r = 0; r < 4; r++) {
                const int i = it + wr * 32 + sr * 16 + rb + r;
                const int j = jt + wc * 32 + sc * 16 + jcol;
                const float vr = gr[sr][sc][r], vi = gi[sr][sc][r];
                *(float2*)&Gb[(i * 128 + j) * 2] = make_float2(vr, vi);
                if (!diag)
                    *(float2*)&Gb[(j * 128 + i) * 2] = make_float2(vr, vi);
            }
}

// =====================================================================
// gram64_mfma (mode 2, d=64). R15: reg prefetch; lb(256,4).
// =====================================================================
__global__ __launch_bounds__(256, 4)
void gram64_mfma_kernel(const float* __restrict__ srcR, const float* __restrict__ srcI,
                        float* __restrict__ Gp, int kPerBlock)
{
    const int b  = blockIdx.y;
    const int k0 = blockIdx.x * kPerBlock;

    const int t    = threadIdx.x;
    const int lane = t & 63;
    const int wave = t >> 6;
    const int wr = wave & 1, wc = wave >> 1;

    __shared__ unsigned short SA[4][2048];   // planes [64 i][32 k]

    const sh8 SGN = {(short)0x8000, (short)0x8000, (short)0x8000, (short)0x8000,
                     (short)0x8000, (short)0x8000, (short)0x8000, (short)0x8000};

    f32x4 gr[2][2], gi[2][2];
    const f32x4 z4 = {0.f, 0.f, 0.f, 0.f};
    #pragma unroll
    for (int x = 0; x < 2; x++)
        #pragma unroll
        for (int y = 0; y < 2; y++) { gr[x][y] = z4; gi[x][y] = z4; }

    const size_t boff = (size_t)b * SSIZE;
    const int nT = kPerBlock >> 5;

    const int kp = t & 15;        // k = 2kp, 2kp+1 within tile
    const int i0 = (t >> 4) * 4;  // i quad

    const int frow = lane & 15;
    const int kg   = lane >> 4;

    float4 qR[2], qI[2];
    auto loadk = [&](int kb) {
        const int ke = kb + 2 * kp;
        const int ko = ke + 1;
        const size_t offE = boff + (size_t)(ke & 127) * 64 + (size_t)(ke >> 7) * 8192 + i0;
        const size_t offO = boff + (size_t)(ko & 127) * 64 + (size_t)(ko >> 7) * 8192 + i0;
        qR[0] = *(const float4*)(srcR + offE);
        qI[0] = *(const float4*)(srcI + offE);
        qR[1] = *(const float4*)(srcR + offO);
        qI[1] = *(const float4*)(srcI + offO);
    };

    loadk(k0);
    for (int kt = 0; kt < nT; kt++) {
        const int kw = 2 * kp;
        #pragma unroll
        for (int c = 0; c < 4; c++) {
            const int i   = i0 + c;
            const int idx = (i * 32 + kw) ^ ((i & 3) << 3);
            unsigned short h0, l0, h1, l1;
            split1(f4c(qR[0], c), h0, l0);
            split1(f4c(qR[1], c), h1, l1);
            *(ushort2*)&SA[0][idx] = make_ushort2(h0, h1);
            *(ushort2*)&SA[1][idx] = make_ushort2(l0, l1);
            split1(f4c(qI[0], c), h0, l0);
            split1(f4c(qI[1], c), h1, l1);
            *(ushort2*)&SA[2][idx] = make_ushort2(h0, h1);
            *(ushort2*)&SA[3][idx] = make_ushort2(l0, l1);
        }
        __syncthreads();

        if (kt + 1 < nT) loadk(k0 + (kt + 1) * 32);

        sh8 a[2][4], na[2][2], bfr[2][4];
        #pragma unroll
        for (int s = 0; s < 2; s++) {
            const int row = wr * 32 + s * 16 + frow;
            #pragma unroll
            for (int p = 0; p < 4; p++) a[s][p] = ldfrag(&SA[p][0], row, kg);
            na[s][0] = a[s][2] ^ SGN;
            na[s][1] = a[s][3] ^ SGN;
        }
        #pragma unroll
        for (int s = 0; s < 2; s++) {
            const int row = wc * 32 + s * 16 + frow;
            #pragma unroll
            for (int p = 0; p < 4; p++) bfr[s][p] = ldfrag(&SA[p][0], row, kg);
        }

        #pragma unroll
        for (int sr = 0; sr < 2; sr++) {
            #pragma unroll
            for (int sc = 0; sc < 2; sc++) {
                f32x4 r = gr[sr][sc], q = gi[sr][sc];
                r = MFMA16(a[sr][0],  bfr[sc][0], r);
                r = MFMA16(a[sr][0],  bfr[sc][1], r);
                r = MFMA16(a[sr][1],  bfr[sc][0], r);
                r = MFMA16(na[sr][0], bfr[sc][2], r);
                r = MFMA16(na[sr][0], bfr[sc][3], r);
                r = MFMA16(na[sr][1], bfr[sc][2], r);
                q = MFMA16(a[sr][0],  bfr[sc][2], q);
                q = MFMA16(a[sr][0],  bfr[sc][3], q);
                q = MFMA16(a[sr][1],  bfr[sc][2], q);
                q = MFMA16(a[sr][2],  bfr[sc][0], q);
                q = MFMA16(a[sr][2],  bfr[sc][1], q);
                q = MFMA16(a[sr][3],  bfr[sc][0], q);
                gr[sr][sc] = r; gi[sr][sc] = q;
            }
        }
        __syncthreads();
    }

    float* Gb = Gp + ((size_t)b * gridDim.x + blockIdx.x) * (64 * 64 * 2);
    const int rb   = (lane >> 4) * 4;
    const int jcol = lane & 15;
    #pragma unroll
    for (int sr = 0; sr < 2; sr++)
        #pragma unroll
        for (int sc = 0; sc < 2; sc++)
            #pragma unroll
            for (int r = 0; r < 4; r++) {
                const int i = wr * 32 + sr * 16 + rb + r;
                const int j = wc * 32 + sc * 16 + jcol;
                *(float2*)&Gb[(i * 64 + j) * 2] = make_float2(gr[sr][sc][r], gi[sr][sc][r]);
            }
}

// ---------------- score/softmax/phase -> routing matrix M ----------------
// Writes M as 4 packed bf16 planes [b][p][d*d]: p=0 MrH, 1 MrL, 2 MiH, 3 MiL
__global__ __launch_bounds__(128)
void score_kernel(const float* __restrict__ G,
                  const float* __restrict__ Wre, const float* __restrict__ Wim,
                  const float* __restrict__ log_tau,
                  unsigned short* __restrict__ Mout, int d)
{
    const int b = blockIdx.y;
    const int i = blockIdx.x;
    const int j = threadIdx.x;

    const float2* Gb = (const float2*)G + (size_t)b * d * d;

    float sre = 0.f, sim = 0.f;
    for (int l = 0; l < d; l++) {
        float wr = Wre[i * d + l];
        float wi = Wim[i * d + l];
        float2 g = Gb[l * d + j];
        sre = fmaf(wr, g.x, sre);
        sre = fmaf(-wi, g.y, sre);
        sim = fmaf(wr, g.y, sim);
        sim = fmaf(wi, g.x, sim);
    }

    float mag = sqrtf(sre * sre + sim * sim);
    float tau = fmaxf(expf(log_tau[0]), 1e-8f);
    float scale = tau * sqrtf((float)SSIZE / (float)d);
    float mval = mag / scale;

    __shared__ float red[128];
    red[j] = mval;
    __syncthreads();
    for (int s = d >> 1; s > 0; s >>= 1) {
        if (j < s) red[j] = fmaxf(red[j], red[j + s]);
        __syncthreads();
    }
    float mx = red[0];
    __syncthreads();
    float e = expf(mval - mx);
    red[j] = e;
    __syncthreads();
    for (int s = d >> 1; s > 0; s >>= 1) {
        if (j < s) red[j] += red[j + s];
        __syncthreads();
    }
    float routing = e / red[0];

    float safe = fmaxf(mag, 1e-8f);
    float pre, pim;
    if (mag > 1e-8f) { pre = sre / safe; pim = sim / safe; }
    else             { pre = 1.f;       pim = 0.f; }

    const float mr = routing * pre;
    const float mi = routing * pim;
    const size_t dd = (size_t)d * d;
    unsigned short h, l;
    split1(mr, h, l);
    Mout[((size_t)b * 4 + 0) * dd + i * d + j] = h;
    Mout[((size_t)b * 4 + 1) * dd + i * d + j] = l;
    split1(mi, h, l);
    Mout[((size_t)b * 4 + 2) * dd + i * d + j] = h;
    Mout[((size_t)b * 4 + 3) * dd + i * d + j] = l;
}

// =====================================================================
// mix128_mfma (modes 0/1, d=128). R15: reg prefetch on M copy + u loads.
// =====================================================================
template<int SI_, int KL2_, int SKH_>
__global__ __launch_bounds__(256, 4)
void mix128_mfma_kernel(const float* __restrict__ srcR, const float* __restrict__ srcI,
                        const unsigned short* __restrict__ Mp,
                        float* __restrict__ dstR, float* __restrict__ dstI)
{
    const int kb0 = blockIdx.x << 6;   // 64-wide k tile
    const int it  = blockIdx.y << 6;   // 64-wide i tile
    const int b   = blockIdx.z;

    const int t    = threadIdx.x;
    const int lane = t & 63;
    const int wave = t >> 6;
    const int wr = wave & 1, wc = wave >> 1;   // wr: k half, wc: i half

    __shared__ unsigned short UP[4][2560];   // u^T planes [kcol 0..63][j 0..31], pitch 40
    __shared__ unsigned short MP[4][2560];   // M   planes [i    0..63][j 0..31], pitch 40

    const sh8 SGN = {(short)0x8000, (short)0x8000, (short)0x8000, (short)0x8000,
                     (short)0x8000, (short)0x8000, (short)0x8000, (short)0x8000};

    f32x4 gr[2][2], gi[2][2];     // [sr: k-sub][sc: i-sub]
    const f32x4 z4 = {0.f, 0.f, 0.f, 0.f};
    #pragma unroll
    for (int x = 0; x < 2; x++)
        #pragma unroll
        for (int y = 0; y < 2; y++) { gr[x][y] = z4; gi[x][y] = z4; }

    const size_t boff = (size_t)b * SSIZE;
    const unsigned short* Mb = Mp + (size_t)b * 4 * 16384;   // 4 planes of 128*128

    #define GADDR(jj, k) (boff + (size_t)(jj) * SI_ + \
        (size_t)((k) >> KL2_) * SKH_ + (size_t)((k) & ((1 << KL2_) - 1)))

    // staging maps
    const int ujp = t & 15;        // j pair: j0 = 2*ujp
    const int uq  = t >> 4;        // k quad: kc0 = 4*uq
    const int mi  = t >> 2;        // i row for M
    const int mj8 = (t & 3) * 8;   // j octet for M

    const int frow = lane & 15;
    const int kg   = lane >> 4;

    uint4 pM[4];
    float4 pR0, pR1, pI0, pI1;
    auto loadjt = [&](int jb) {
        const int src = (it + mi) * 128 + jb + mj8;
        #pragma unroll
        for (int p = 0; p < 4; p++) pM[p] = *(const uint4*)&Mb[p * 16384 + src];
        const int j0 = 2 * ujp;
        const size_t o0 = GADDR(jb + j0,     kb0 + 4 * uq);
        const size_t o1 = GADDR(jb + j0 + 1, kb0 + 4 * uq);
        pR0 = *(const float4*)(srcR + o0);
        pR1 = *(const float4*)(srcR + o1);
        pI0 = *(const float4*)(srcI + o0);
        pI1 = *(const float4*)(srcI + o1);
    };

    loadjt(0);
    for (int jt = 0; jt < 4; jt++) {
        // ---- write staged regs to LDS
        {
            const int idx = mi * 40 + mj8;
            #pragma unroll
            for (int p = 0; p < 4; p++) *(uint4*)&MP[p][idx] = pM[p];
        }
        {
            const int j0 = 2 * ujp;
            #pragma unroll
            for (int c = 0; c < 4; c++) {
                const int kc  = 4 * uq + c;
                const int idx = kc * 40 + j0;
                unsigned hh, ll;
                split2(f4c(pR0, c), f4c(pR1, c), hh, ll);
                *(unsigned*)&UP[0][idx] = hh;
                *(unsigned*)&UP[1][idx] = ll;
                split2(f4c(pI0, c), f4c(pI1, c), hh, ll);
                *(unsigned*)&UP[2][idx] = hh;
                *(unsigned*)&UP[3][idx] = ll;
            }
        }
        __syncthreads();

        if (jt + 1 < 4) loadjt((jt + 1) * 32);

        sh8 a[2][4], na[2][2], bfr[2][4];
        #pragma unroll
        for (int s = 0; s < 2; s++) {
            const int row = wr * 32 + s * 16 + frow;
            #pragma unroll
            for (int p = 0; p < 4; p++) a[s][p] = ldfrag40(&UP[p][0], row, kg);
            na[s][0] = a[s][2] ^ SGN;
            na[s][1] = a[s][3] ^ SGN;
        }
        #pragma unroll
        for (int s = 0; s < 2; s++) {
            const int row = wc * 32 + s * 16 + frow;
            #pragma unroll
            for (int p = 0; p < 4; p++) bfr[s][p] = ldfrag40(&MP[p][0], row, kg);
        }

        #pragma unroll
        for (int sr = 0; sr < 2; sr++) {
            #pragma unroll
            for (int sc = 0; sc < 2; sc++) {
                f32x4 r = gr[sr][sc], q = gi[sr][sc];
                // Dr = Ur*Mr - Ui*Mi (split HH+HL+LH)
                r = MFMA16(a[sr][0],  bfr[sc][0], r);
                r = MFMA16(a[sr][0],  bfr[sc][1], r);
                r = MFMA16(a[sr][1],  bfr[sc][0], r);
                r = MFMA16(na[sr][0], bfr[sc][2], r);
                r = MFMA16(na[sr][0], bfr[sc][3], r);
                r = MFMA16(na[sr][1], bfr[sc][2], r);
                // Di = Ur*Mi + Ui*Mr
                q = MFMA16(a[sr][0],  bfr[sc][2], q);
                q = MFMA16(a[sr][0],  bfr[sc][3], q);
                q = MFMA16(a[sr][1],  bfr[sc][2], q);
                q = MFMA16(a[sr][2],  bfr[sc][0], q);
                q = MFMA16(a[sr][2],  bfr[sc][1], q);
                q = MFMA16(a[sr][3],  bfr[sc][0], q);
                gr[sr][sc] = r; gi[sr][sc] = q;
            }
        }
        __syncthreads();
    }

    // epilogue: lane holds 4 consecutive k (rows) at one i (col) -> float4
    #pragma unroll
    for (int sr = 0; sr < 2; sr++)
        #pragma unroll
        for (int sc = 0; sc < 2; sc++) {
            const int k = kb0 + wr * 32 + sr * 16 + 4 * (lane >> 4);
            const int i = it  + wc * 32 + sc * 16 + (lane & 15);
            const size_t o = boff + (size_t)i * SI_ +
                (size_t)(k >> KL2_) * SKH_ + (size_t)(k & ((1 << KL2_) - 1));
            *(float4*)(dstR + o) = make_float4(gr[sr][sc][0], gr[sr][sc][1],
                                               gr[sr][sc][2], gr[sr][sc][3]);
            *(float4*)(dstI + o) = make_float4(gi[sr][sc][0], gi[sr][sc][1],
                                               gi[sr][sc][2], gi[sr][sc][3]);
        }
    #undef GADDR
}

// =====================================================================
// mix64_mfma (mode 2, d=64). R15: reg prefetch.
// =====================================================================
__global__ __launch_bounds__(256, 4)
void mix64_mfma_kernel(const float* __restrict__ srcR, const float* __restrict__ srcI,
                       const unsigned short* __restrict__ Mp,
                       float* __restrict__ dstR, float* __restrict__ dstI)
{
    const int kb0 = blockIdx.x << 6;   // 64-wide k tile
    const int b   = blockIdx.y;

    const int t    = threadIdx.x;
    const int lane = t & 63;
    const int wave = t >> 6;
    const int wr = wave & 1, wc = wave >> 1;   // wr: i half, wc: k half

    __shared__ unsigned short UP[4][2560];   // u^T planes [kcol][j 0..31], pitch 40
    __shared__ unsigned short MP[4][2560];   // M   planes [i   ][j 0..31], pitch 40

    const sh8 SGN = {(short)0x8000, (short)0x8000, (short)0x8000, (short)0x8000,
                     (short)0x8000, (short)0x8000, (short)0x8000, (short)0x8000};

    f32x4 gr[2][2], gi[2][2];     // [sr: i-sub][sc: k-sub]
    const f32x4 z4 = {0.f, 0.f, 0.f, 0.f};
    #pragma unroll
    for (int x = 0; x < 2; x++)
        #pragma unroll
        for (int y = 0; y < 2; y++) { gr[x][y] = z4; gi[x][y] = z4; }

    const size_t boff  = (size_t)b * SSIZE;
    const unsigned short* Mb = Mp + (size_t)b * 4 * 4096;    // 4 planes of 64*64
    const size_t koffb = (size_t)(kb0 & 127) * 64 + (size_t)(kb0 >> 7) * 8192;

    // staging maps
    const int mi  = t >> 2;        // i row for M
    const int mj8 = (t & 3) * 8;   // j octet for M
    const int ujq = t & 7;         // j quad: j0 = 4*ujq
    const int ukc = t >> 3;        // kcol 0..31 (+32 second item)

    const int frow = lane & 15;
    const int kg   = lane >> 4;

    uint4 pM[4];
    float4 pR[2], pI[2];
    auto loadjt = [&](int jb) {
        const int src = mi * 64 + jb + mj8;
        #pragma unroll
        for (int p = 0; p < 4; p++) pM[p] = *(const uint4*)&Mb[p * 4096 + src];
        #pragma unroll
        for (int m = 0; m < 2; m++) {
            const int kc = ukc + 32 * m;
            const size_t o = boff + koffb + (size_t)kc * 64 + jb + 4 * ujq;
            pR[m] = *(const float4*)(srcR + o);
            pI[m] = *(const float4*)(srcI + o);
        }
    };

    loadjt(0);
    for (int jt = 0; jt < 2; jt++) {
        {
            const int idx = mi * 40 + mj8;
            #pragma unroll
            for (int p = 0; p < 4; p++) *(uint4*)&MP[p][idx] = pM[p];
        }
        #pragma unroll
        for (int m = 0; m < 2; m++) {
            const int kc = ukc + 32 * m;
            const int idx = kc * 40 + 4 * ujq;
            unsigned h0, l0, h1, l1;
            split2(pR[m].x, pR[m].y, h0, l0); split2(pR[m].z, pR[m].w, h1, l1);
            *(uint2*)&UP[0][idx] = make_uint2(h0, h1);
            *(uint2*)&UP[1][idx] = make_uint2(l0, l1);
            split2(pI[m].x, pI[m].y, h0, l0); split2(pI[m].z, pI[m].w, h1, l1);
            *(uint2*)&UP[2][idx] = make_uint2(h0, h1);
            *(uint2*)&UP[3][idx] = make_uint2(l0, l1);
        }
        __syncthreads();

        if (jt + 1 < 2) loadjt((jt + 1) * 32);

        sh8 a[2][4], na[2][2], bfr[2][4];
        #pragma unroll
        for (int s = 0; s < 2; s++) {
            const int row = wr * 32 + s * 16 + frow;
            #pragma unroll
            for (int p = 0; p < 4; p++) a[s][p] = ldfrag40(&MP[p][0], row, kg);
            na[s][0] = a[s][2] ^ SGN;
            na[s][1] = a[s][3] ^ SGN;
        }
        #pragma unroll
        for (int s = 0; s < 2; s++) {
            const int row = wc * 32 + s * 16 + frow;
            #pragma unroll
            for (int p = 0; p < 4; p++) bfr[s][p] = ldfrag40(&UP[p][0], row, kg);
        }

        #pragma unroll
        for (int sr = 0; sr < 2; sr++) {
            #pragma unroll
            for (int sc = 0; sc < 2; sc++) {
                f32x4 r = gr[sr][sc], q = gi[sr][sc];
                r = MFMA16(a[sr][0],  bfr[sc][0], r);
                r = MFMA16(a[sr][0],  bfr[sc][1], r);
                r = MFMA16(a[sr][1],  bfr[sc][0], r);
                r = MFMA16(na[sr][0], bfr[sc][2], r);
                r = MFMA16(na[sr][0], bfr[sc][3], r);
                r = MFMA16(na[sr][1], bfr[sc][2], r);
                q = MFMA16(a[sr][0],  bfr[sc][2], q);
                q = MFMA16(a[sr][0],  bfr[sc][3], q);
                q = MFMA16(a[sr][1],  bfr[sc][2], q);
                q = MFMA16(a[sr][2],  bfr[sc][0], q);
                q = MFMA16(a[sr][2],  bfr[sc][1], q);
                q = MFMA16(a[sr][3],  bfr[sc][0], q);
                gr[sr][sc] = r; gi[sr][sc] = q;
            }
        }
        __syncthreads();
    }

    // epilogue: lane holds 4 consecutive i (rows) at one kcol (col) -> float4
    #pragma unroll
    for (int sr = 0; sr < 2; sr++)
        #pragma unroll
        for (int sc = 0; sc < 2; sc++) {
            const int i  = wr * 32 + sr * 16 + 4 * (lane >> 4);
            const int kc = wc * 32 + sc * 16 + (lane & 15);
            const size_t o = boff + koffb + (size_t)kc * 64 + i;
            *(float4*)(dstR + o) = make_float4(gr[sr][sc][0], gr[sr][sc][1],
                                               gr[sr][sc][2], gr[sr][sc][3]);
            *(float4*)(dstI + o) = make_float4(gi[sr][sc][0], gi[sr][sc][1],
                                               gi[sr][sc][2], gi[sr][sc][3]);
        }
}

extern "C" void kernel_launch(void* const* d_in, const int* in_sizes, int n_in,
                              void* d_out, int out_size, void* d_ws, size_t ws_size,
                              hipStream_t stream)
{
    const float* xr  = (const float*)d_in[0];
    const float* xi  = (const float*)d_in[1];
    const float* w0r = (const float*)d_in[2];
    const float* w0i = (const float*)d_in[3];
    const float* w1r = (const float*)d_in[4];
    const float* w1i = (const float*)d_in[5];
    const float* w2r = (const float*)d_in[6];
    const float* w2i = (const float*)d_in[7];
    const float* lt  = (const float*)d_in[8];

    float* outR = (float*)d_out;
    float* outI = outR + (size_t)BATCH * SSIZE;

    float*  wsR = (float*)d_ws;
    float*  wsI = wsR + (size_t)BATCH * SSIZE;
    float*  Gf  = wsI + (size_t)BATCH * SSIZE;
    // M planes: [b][4][d*d] ushort. d=128: 8*4*16384*2B = 1MB.
    unsigned short* Mp = (unsigned short*)(Gf + (size_t)BATCH * 128 * 128 * 2);

    // Partial slabs span the contiguous DEAD R+I pair (64 MB each):
    //  mode 0: outR..outI; mode 1: wsR..wsI; mode 2: outR..outI.
    // NS=32 (d=128): 33.6MB < 64MB. grid 3*32*8 = 768 = 3/CU.
    // NS=128 (d=64): 33.6MB < 64MB. grid 128*8 = 1024 = 4/CU.

    // ---------------- mode 0: d=128, SI=8192, KL2=13
    gram_mfma_kernel<8192, 13, 0><<<dim3(3, 32, BATCH), 256, 0, stream>>>(xr, xi, outR, 256);
    reduce_kernel<32, 8192><<<dim3(256), 256, 0, stream>>>((const float4*)outR, (float4*)Gf);
    score_kernel<<<dim3(128, BATCH), 128, 0, stream>>>(Gf, w0r, w0i, lt, Mp, 128);
    mix128_mfma_kernel<8192, 13, 0><<<dim3(128, 2, BATCH), 256, 0, stream>>>(xr, xi, Mp, outR, outI);

    // ---------------- mode 1: d=128, SI=64, KL2=6, SKH=8192
    gram_mfma_kernel<64, 6, 8192><<<dim3(3, 32, BATCH), 256, 0, stream>>>(outR, outI, wsR, 256);
    reduce_kernel<32, 8192><<<dim3(256), 256, 0, stream>>>((const float4*)wsR, (float4*)Gf);
    score_kernel<<<dim3(128, BATCH), 128, 0, stream>>>(Gf, w1r, w1i, lt, Mp, 128);
    mix128_mfma_kernel<64, 6, 8192><<<dim3(128, 2, BATCH), 256, 0, stream>>>(outR, outI, Mp, wsR, wsI);

    // ---------------- mode 2: d=64, SI=1, k: (k&127)*64 + (k>>7)*8192
    gram64_mfma_kernel<<<dim3(128, BATCH), 256, 0, stream>>>(wsR, wsI, outR, 128);
    reduce_kernel<128, 2048><<<dim3(64), 256, 0, stream>>>((const float4*)outR, (float4*)Gf);
    score_kernel<<<dim3(64, BATCH), 64, 0, stream>>>(Gf, w2r, w2i, lt, Mp, 64);
    mix64_mfma_kernel<<<dim3(256, BATCH), 256, 0, stream>>>(wsR, wsI, Mp, outR, outI);
}

// Round 11
// 427.983 us; speedup vs baseline: 1.0734x; 1.0734x over previous
//
#include <hip/hip_runtime.h>
#include <math.h>

#define BATCH 8
#define SSIZE 1048576   // 128*128*64

// R16 (resubmit R17): revert R15 prefetch (R9 post-mortem: mix128 spilled --
// WRITE_SIZE 66->189MB scratch traffic, dur 46->66us; gram prefetch
// ~neutral). Bodies restored to R14 (measured 422.0us). One new change:
// gram_mfma NS 32->64 (slab = exactly the 64MiB dead R+I pair), grid 1536 =
// 6 blocks/CU, lb(256,3)->(256,4) => 4 resident (128KB LDS, VGPR 56 << 128
// budget). reduce modes 0/1 -> NS=64. Lever = resident-block TLP (R4->R7).

typedef short sh8 __attribute__((ext_vector_type(8)));
typedef float f32x4 __attribute__((ext_vector_type(4)));

#define MFMA16(a, b, c) __builtin_amdgcn_mfma_f32_16x16x32_bf16((a), (b), (c), 0, 0, 0)

__device__ __forceinline__ unsigned short bf_rne(float x) {
    unsigned u = __float_as_uint(x);
    unsigned r = u + 0x7fffu + ((u >> 16) & 1u);
    return (unsigned short)(r >> 16);
}

// split x into hi + lo bf16 (both RNE)
__device__ __forceinline__ void split1(float x, unsigned short &h, unsigned short &l) {
    h = bf_rne(x);
    float hf = __uint_as_float((unsigned)h << 16);
    l = bf_rne(x - hf);
}

// split two floats, pack hi pair / lo pair as u32 (a in low 16, b in high)
__device__ __forceinline__ void split2(float a, float b, unsigned &hh, unsigned &ll) {
    unsigned short ha = bf_rne(a), hb = bf_rne(b);
    hh = (unsigned)ha | ((unsigned)hb << 16);
    float ra = a - __uint_as_float((unsigned)ha << 16);
    float rb = b - __uint_as_float((unsigned)hb << 16);
    ll = (unsigned)bf_rne(ra) | ((unsigned)bf_rne(rb) << 16);
}

__device__ __forceinline__ float f4c(const float4 &v, int c) {
    return c == 0 ? v.x : c == 1 ? v.y : c == 2 ? v.z : v.w;
}

// fragment load, pitch-32 planes with XOR swizzle (gram kernels, proven)
__device__ __forceinline__ sh8 ldfrag(const unsigned short *pl, int row, int kg) {
    const int idx = (row * 32 + kg * 8) ^ ((row & 3) << 3);
    return *(const sh8 *)(pl + idx);
}

// fragment load, pitch-40 planes, no swizzle (mix kernels; bank-optimal)
__device__ __forceinline__ sh8 ldfrag40(const unsigned short *pl, int row, int kg) {
    return *(const sh8 *)(pl + row * 40 + kg * 8);
}

// ---------------- partial-slab reduce: out[b][r] = sum_s in[b][s][r] --------
template<int NS, int PERB>   // PERB in float4 units
__global__ __launch_bounds__(256)
void reduce_kernel(const float4* __restrict__ in, float4* __restrict__ out) {
    const int gid = blockIdx.x * blockDim.x + threadIdx.x;
    const int b = gid / PERB, r = gid - b * PERB;
    const float4* p = in + (size_t)b * NS * PERB + r;
    float4 a = p[0];
    #pragma unroll 8
    for (int s = 1; s < NS; s++) {
        const float4 v = p[(size_t)s * PERB];
        a.x += v.x; a.y += v.y; a.z += v.z; a.w += v.w;
    }
    out[gid] = a;
}

// =====================================================================
// gram_mfma (modes 0/1, d=128): G = u u^T, symmetric. R14 body;
// R16: NS=64 (grid 3x64x8=1536 = 6 blocks/CU), lb(256,4) = 4 resident.
// =====================================================================
template<int SI_, int KL2_, int SKH_>
__global__ __launch_bounds__(256, 4)
void gram_mfma_kernel(const float* __restrict__ srcR, const float* __restrict__ srcI,
                      float* __restrict__ Gp, int kPerBlock)
{
    const int tile = blockIdx.x;             // 0,1,2
    const int it = (tile == 2) ? 64 : 0;
    const int jt = (tile == 0) ? 0 : 64;
    const bool diag = (it == jt);
    const int b  = blockIdx.z;
    const int k0 = blockIdx.y * kPerBlock;

    const int t    = threadIdx.x;
    const int lane = t & 63;
    const int wave = t >> 6;          // 0..3
    const int wr = wave & 1, wc = wave >> 1;

    __shared__ unsigned short SA[4][2048];   // planes rH,rL,iH,iL  [64 rows][32 k]
    __shared__ unsigned short SB[4][2048];

    const sh8 SGN = {(short)0x8000, (short)0x8000, (short)0x8000, (short)0x8000,
                     (short)0x8000, (short)0x8000, (short)0x8000, (short)0x8000};

    f32x4 gr[2][2], gi[2][2];
    const f32x4 z4 = {0.f, 0.f, 0.f, 0.f};
    #pragma unroll
    for (int x = 0; x < 2; x++)
        #pragma unroll
        for (int y = 0; y < 2; y++) { gr[x][y] = z4; gi[x][y] = z4; }

    const size_t boff = (size_t)b * SSIZE;
    const int nT = kPerBlock >> 5;

    const int kq   = t & 7;
    const int row2 = t >> 3;

    const int frow = lane & 15;
    const int kg   = lane >> 4;

    #define GADDR(ii, k) (boff + (size_t)(ii) * SI_ + \
        (size_t)((k) >> KL2_) * SKH_ + (size_t)((k) & ((1 << KL2_) - 1)))

    for (int kt = 0; kt < nT; kt++) {
        const int kb = k0 + kt * 32;
        #pragma unroll
        for (int m = 0; m < 2; m++) {
            const int row = row2 + 32 * m;
            const int idx = (row * 32 + kq * 4) ^ ((row & 3) << 3);
            {
                const size_t off = GADDR(it + row, kb + kq * 4);
                const float4 R = *(const float4*)(srcR + off);
                const float4 I = *(const float4*)(srcI + off);
                ushort4 rh, rl, ih, il;
                split1(R.x, rh.x, rl.x); split1(R.y, rh.y, rl.y);
                split1(R.z, rh.z, rl.z); split1(R.w, rh.w, rl.w);
                split1(I.x, ih.x, il.x); split1(I.y, ih.y, il.y);
                split1(I.z, ih.z, il.z); split1(I.w, ih.w, il.w);
                *(ushort4*)&SA[0][idx] = rh;
                *(ushort4*)&SA[1][idx] = rl;
                *(ushort4*)&SA[2][idx] = ih;
                *(ushort4*)&SA[3][idx] = il;
            }
            if (!diag) {
                const size_t off = GADDR(jt + row, kb + kq * 4);
                const float4 R = *(const float4*)(srcR + off);
                const float4 I = *(const float4*)(srcI + off);
                ushort4 rh, rl, ih, il;
                split1(R.x, rh.x, rl.x); split1(R.y, rh.y, rl.y);
                split1(R.z, rh.z, rl.z); split1(R.w, rh.w, rl.w);
                split1(I.x, ih.x, il.x); split1(I.y, ih.y, il.y);
                split1(I.z, ih.z, il.z); split1(I.w, ih.w, il.w);
                *(ushort4*)&SB[0][idx] = rh;
                *(ushort4*)&SB[1][idx] = rl;
                *(ushort4*)&SB[2][idx] = ih;
                *(ushort4*)&SB[3][idx] = il;
            }
        }
        __syncthreads();

        unsigned short (*BP)[2048] = diag ? SA : SB;

        sh8 a[2][4], na[2][2], bfr[2][4];
        #pragma unroll
        for (int s = 0; s < 2; s++) {
            const int row = wr * 32 + s * 16 + frow;
            #pragma unroll
            for (int p = 0; p < 4; p++) a[s][p] = ldfrag(&SA[p][0], row, kg);
            na[s][0] = a[s][2] ^ SGN;
            na[s][1] = a[s][3] ^ SGN;
        }
        #pragma unroll
        for (int s = 0; s < 2; s++) {
            const int row = wc * 32 + s * 16 + frow;
            #pragma unroll
            for (int p = 0; p < 4; p++) bfr[s][p] = ldfrag(&BP[p][0], row, kg);
        }

        #pragma unroll
        for (int sr = 0; sr < 2; sr++) {
            #pragma unroll
            for (int sc = 0; sc < 2; sc++) {
                f32x4 r = gr[sr][sc], q = gi[sr][sc];
                r = MFMA16(a[sr][0],  bfr[sc][0], r);
                r = MFMA16(a[sr][0],  bfr[sc][1], r);
                r = MFMA16(a[sr][1],  bfr[sc][0], r);
                r = MFMA16(na[sr][0], bfr[sc][2], r);
                r = MFMA16(na[sr][0], bfr[sc][3], r);
                r = MFMA16(na[sr][1], bfr[sc][2], r);
                q = MFMA16(a[sr][0],  bfr[sc][2], q);
                q = MFMA16(a[sr][0],  bfr[sc][3], q);
                q = MFMA16(a[sr][1],  bfr[sc][2], q);
                q = MFMA16(a[sr][2],  bfr[sc][0], q);
                q = MFMA16(a[sr][2],  bfr[sc][1], q);
                q = MFMA16(a[sr][3],  bfr[sc][0], q);
                gr[sr][sc] = r; gi[sr][sc] = q;
            }
        }
        __syncthreads();
    }
    #undef GADDR

    float* Gb = Gp + ((size_t)b * gridDim.y + blockIdx.y) * (128 * 128 * 2);
    const int rb   = (lane >> 4) * 4;
    const int jcol = lane & 15;
    #pragma unroll
    for (int sr = 0; sr < 2; sr++)
        #pragma unroll
        for (int sc = 0; sc < 2; sc++)
            #pragma unroll
            for (int r = 0; r < 4; r++) {
                const int i = it + wr * 32 + sr * 16 + rb + r;
                const int j = jt + wc * 32 + sc * 16 + jcol;
                const float vr = gr[sr][sc][r], vi = gi[sr][sc][r];
                *(float2*)&Gb[(i * 128 + j) * 2] = make_float2(vr, vi);
                if (!diag)
                    *(float2*)&Gb[(j * 128 + i) * 2] = make_float2(vr, vi);
            }
}

// =====================================================================
// gram64_mfma (mode 2, d=64). R14 body (proven); lb(256,4).
// =====================================================================
__global__ __launch_bounds__(256, 4)
void gram64_mfma_kernel(const float* __restrict__ srcR, const float* __restrict__ srcI,
                        float* __restrict__ Gp, int kPerBlock)
{
    const int b  = blockIdx.y;
    const int k0 = blockIdx.x * kPerBlock;

    const int t    = threadIdx.x;
    const int lane = t & 63;
    const int wave = t >> 6;
    const int wr = wave & 1, wc = wave >> 1;

    __shared__ unsigned short SA[4][2048];   // planes [64 i][32 k]

    const sh8 SGN = {(short)0x8000, (short)0x8000, (short)0x8000, (short)0x8000,
                     (short)0x8000, (short)0x8000, (short)0x8000, (short)0x8000};

    f32x4 gr[2][2], gi[2][2];
    const f32x4 z4 = {0.f, 0.f, 0.f, 0.f};
    #pragma unroll
    for (int x = 0; x < 2; x++)
        #pragma unroll
        for (int y = 0; y < 2; y++) { gr[x][y] = z4; gi[x][y] = z4; }

    const size_t boff = (size_t)b * SSIZE;
    const int nT = kPerBlock >> 5;

    const int kp = t & 15;        // k = 2kp, 2kp+1 within tile
    const int i0 = (t >> 4) * 4;  // i quad

    const int frow = lane & 15;
    const int kg   = lane >> 4;

    for (int kt = 0; kt < nT; kt++) {
        const int kb = k0 + kt * 32;
        const int ke = kb + 2 * kp;
        const int ko = ke + 1;
        const size_t offE = boff + (size_t)(ke & 127) * 64 + (size_t)(ke >> 7) * 8192 + i0;
        const size_t offO = boff + (size_t)(ko & 127) * 64 + (size_t)(ko >> 7) * 8192 + i0;
        const float4 R0 = *(const float4*)(srcR + offE);
        const float4 I0 = *(const float4*)(srcI + offE);
        const float4 R1 = *(const float4*)(srcR + offO);
        const float4 I1 = *(const float4*)(srcI + offO);
        const int kw = 2 * kp;
        #pragma unroll
        for (int c = 0; c < 4; c++) {
            const int i   = i0 + c;
            const int idx = (i * 32 + kw) ^ ((i & 3) << 3);
            unsigned short h0, l0, h1, l1;
            split1(f4c(R0, c), h0, l0);
            split1(f4c(R1, c), h1, l1);
            *(ushort2*)&SA[0][idx] = make_ushort2(h0, h1);
            *(ushort2*)&SA[1][idx] = make_ushort2(l0, l1);
            split1(f4c(I0, c), h0, l0);
            split1(f4c(I1, c), h1, l1);
            *(ushort2*)&SA[2][idx] = make_ushort2(h0, h1);
            *(ushort2*)&SA[3][idx] = make_ushort2(l0, l1);
        }
        __syncthreads();

        sh8 a[2][4], na[2][2], bfr[2][4];
        #pragma unroll
        for (int s = 0; s < 2; s++) {
            const int row = wr * 32 + s * 16 + frow;
            #pragma unroll
            for (int p = 0; p < 4; p++) a[s][p] = ldfrag(&SA[p][0], row, kg);
            na[s][0] = a[s][2] ^ SGN;
            na[s][1] = a[s][3] ^ SGN;
        }
        #pragma unroll
        for (int s = 0; s < 2; s++) {
            const int row = wc * 32 + s * 16 + frow;
            #pragma unroll
            for (int p = 0; p < 4; p++) bfr[s][p] = ldfrag(&SA[p][0], row, kg);
        }

        #pragma unroll
        for (int sr = 0; sr < 2; sr++) {
            #pragma unroll
            for (int sc = 0; sc < 2; sc++) {
                f32x4 r = gr[sr][sc], q = gi[sr][sc];
                r = MFMA16(a[sr][0],  bfr[sc][0], r);
                r = MFMA16(a[sr][0],  bfr[sc][1], r);
                r = MFMA16(a[sr][1],  bfr[sc][0], r);
                r = MFMA16(na[sr][0], bfr[sc][2], r);
                r = MFMA16(na[sr][0], bfr[sc][3], r);
                r = MFMA16(na[sr][1], bfr[sc][2], r);
                q = MFMA16(a[sr][0],  bfr[sc][2], q);
                q = MFMA16(a[sr][0],  bfr[sc][3], q);
                q = MFMA16(a[sr][1],  bfr[sc][2], q);
                q = MFMA16(a[sr][2],  bfr[sc][0], q);
                q = MFMA16(a[sr][2],  bfr[sc][1], q);
                q = MFMA16(a[sr][3],  bfr[sc][0], q);
                gr[sr][sc] = r; gi[sr][sc] = q;
            }
        }
        __syncthreads();
    }

    float* Gb = Gp + ((size_t)b * gridDim.x + blockIdx.x) * (64 * 64 * 2);
    const int rb   = (lane >> 4) * 4;
    const int jcol = lane & 15;
    #pragma unroll
    for (int sr = 0; sr < 2; sr++)
        #pragma unroll
        for (int sc = 0; sc < 2; sc++)
            #pragma unroll
            for (int r = 0; r < 4; r++) {
                const int i = wr * 32 + sr * 16 + rb + r;
                const int j = wc * 32 + sc * 16 + jcol;
                *(float2*)&Gb[(i * 64 + j) * 2] = make_float2(gr[sr][sc][r], gi[sr][sc][r]);
            }
}

// ---------------- score/softmax/phase -> routing matrix M ----------------
// Writes M as 4 packed bf16 planes [b][p][d*d]: p=0 MrH, 1 MrL, 2 MiH, 3 MiL
__global__ __launch_bounds__(128)
void score_kernel(const float* __restrict__ G,
                  const float* __restrict__ Wre, const float* __restrict__ Wim,
                  const float* __restrict__ log_tau,
                  unsigned short* __restrict__ Mout, int d)
{
    const int b = blockIdx.y;
    const int i = blockIdx.x;
    const int j = threadIdx.x;

    const float2* Gb = (const float2*)G + (size_t)b * d * d;

    float sre = 0.f, sim = 0.f;
    for (int l = 0; l < d; l++) {
        float wr = Wre[i * d + l];
        float wi = Wim[i * d + l];
        float2 g = Gb[l * d + j];
        sre = fmaf(wr, g.x, sre);
        sre = fmaf(-wi, g.y, sre);
        sim = fmaf(wr, g.y, sim);
        sim = fmaf(wi, g.x, sim);
    }

    float mag = sqrtf(sre * sre + sim * sim);
    float tau = fmaxf(expf(log_tau[0]), 1e-8f);
    float scale = tau * sqrtf((float)SSIZE / (float)d);
    float mval = mag / scale;

    __shared__ float red[128];
    red[j] = mval;
    __syncthreads();
    for (int s = d >> 1; s > 0; s >>= 1) {
        if (j < s) red[j] = fmaxf(red[j], red[j + s]);
        __syncthreads();
    }
    float mx = red[0];
    __syncthreads();
    float e = expf(mval - mx);
    red[j] = e;
    __syncthreads();
    for (int s = d >> 1; s > 0; s >>= 1) {
        if (j < s) red[j] += red[j + s];
        __syncthreads();
    }
    float routing = e / red[0];

    float safe = fmaxf(mag, 1e-8f);
    float pre, pim;
    if (mag > 1e-8f) { pre = sre / safe; pim = sim / safe; }
    else             { pre = 1.f;       pim = 0.f; }

    const float mr = routing * pre;
    const float mi = routing * pim;
    const size_t dd = (size_t)d * d;
    unsigned short h, l;
    split1(mr, h, l);
    Mout[((size_t)b * 4 + 0) * dd + i * d + j] = h;
    Mout[((size_t)b * 4 + 1) * dd + i * d + j] = l;
    split1(mi, h, l);
    Mout[((size_t)b * 4 + 2) * dd + i * d + j] = h;
    Mout[((size_t)b * 4 + 3) * dd + i * d + j] = l;
}

// =====================================================================
// mix128_mfma (modes 0/1, d=128). R14 body (proven, no prefetch).
// =====================================================================
template<int SI_, int KL2_, int SKH_>
__global__ __launch_bounds__(256, 4)
void mix128_mfma_kernel(const float* __restrict__ srcR, const float* __restrict__ srcI,
                        const unsigned short* __restrict__ Mp,
                        float* __restrict__ dstR, float* __restrict__ dstI)
{
    const int kb0 = blockIdx.x << 6;   // 64-wide k tile
    const int it  = blockIdx.y << 6;   // 64-wide i tile
    const int b   = blockIdx.z;

    const int t    = threadIdx.x;
    const int lane = t & 63;
    const int wave = t >> 6;
    const int wr = wave & 1, wc = wave >> 1;   // wr: k half, wc: i half

    __shared__ unsigned short UP[4][2560];   // u^T planes [kcol 0..63][j 0..31], pitch 40
    __shared__ unsigned short MP[4][2560];   // M   planes [i    0..63][j 0..31], pitch 40

    const sh8 SGN = {(short)0x8000, (short)0x8000, (short)0x8000, (short)0x8000,
                     (short)0x8000, (short)0x8000, (short)0x8000, (short)0x8000};

    f32x4 gr[2][2], gi[2][2];     // [sr: k-sub][sc: i-sub]
    const f32x4 z4 = {0.f, 0.f, 0.f, 0.f};
    #pragma unroll
    for (int x = 0; x < 2; x++)
        #pragma unroll
        for (int y = 0; y < 2; y++) { gr[x][y] = z4; gi[x][y] = z4; }

    const size_t boff = (size_t)b * SSIZE;
    const unsigned short* Mb = Mp + (size_t)b * 4 * 16384;   // 4 planes of 128*128

    #define GADDR(jj, k) (boff + (size_t)(jj) * SI_ + \
        (size_t)((k) >> KL2_) * SKH_ + (size_t)((k) & ((1 << KL2_) - 1)))

    // staging maps
    const int ujp = t & 15;        // j pair: j0 = 2*ujp
    const int uq  = t >> 4;        // k quad: kc0 = 4*uq
    const int mi  = t >> 2;        // i row for M
    const int mj8 = (t & 3) * 8;   // j octet for M

    const int frow = lane & 15;
    const int kg   = lane >> 4;

    for (int jt = 0; jt < 4; jt++) {
        const int jb = jt * 32;
        // ---- stage M: pure copy of pre-split planes (16B loads/stores)
        {
            const int src = (it + mi) * 128 + jb + mj8;
            const int idx = mi * 40 + mj8;
            #pragma unroll
            for (int p = 0; p < 4; p++)
                *(uint4*)&MP[p][idx] = *(const uint4*)&Mb[p * 16384 + src];
        }
        // ---- stage u^T: 64 kcol x 32 j, uint stores (split in-kernel)
        {
            const int j0 = 2 * ujp;
            const size_t o0 = GADDR(jb + j0,     kb0 + 4 * uq);
            const size_t o1 = GADDR(jb + j0 + 1, kb0 + 4 * uq);
            const float4 R0 = *(const float4*)(srcR + o0);
            const float4 R1 = *(const float4*)(srcR + o1);
            const float4 I0 = *(const float4*)(srcI + o0);
            const float4 I1 = *(const float4*)(srcI + o1);
            #pragma unroll
            for (int c = 0; c < 4; c++) {
                const int kc  = 4 * uq + c;
                const int idx = kc * 40 + j0;
                unsigned hh, ll;
                split2(f4c(R0, c), f4c(R1, c), hh, ll);
                *(unsigned*)&UP[0][idx] = hh;
                *(unsigned*)&UP[1][idx] = ll;
                split2(f4c(I0, c), f4c(I1, c), hh, ll);
                *(unsigned*)&UP[2][idx] = hh;
                *(unsigned*)&UP[3][idx] = ll;
            }
        }
        __syncthreads();

        sh8 a[2][4], na[2][2], bfr[2][4];
        #pragma unroll
        for (int s = 0; s < 2; s++) {
            const int row = wr * 32 + s * 16 + frow;
            #pragma unroll
            for (int p = 0; p < 4; p++) a[s][p] = ldfrag40(&UP[p][0], row, kg);
            na[s][0] = a[s][2] ^ SGN;
            na[s][1] = a[s][3] ^ SGN;
        }
        #pragma unroll
        for (int s = 0; s < 2; s++) {
            const int row = wc * 32 + s * 16 + frow;
            #pragma unroll
            for (int p = 0; p < 4; p++) bfr[s][p] = ldfrag40(&MP[p][0], row, kg);
        }

        #pragma unroll
        for (int sr = 0; sr < 2; sr++) {
            #pragma unroll
            for (int sc = 0; sc < 2; sc++) {
                f32x4 r = gr[sr][sc], q = gi[sr][sc];
                // Dr = Ur*Mr - Ui*Mi (split HH+HL+LH)
                r = MFMA16(a[sr][0],  bfr[sc][0], r);
                r = MFMA16(a[sr][0],  bfr[sc][1], r);
                r = MFMA16(a[sr][1],  bfr[sc][0], r);
                r = MFMA16(na[sr][0], bfr[sc][2], r);
                r = MFMA16(na[sr][0], bfr[sc][3], r);
                r = MFMA16(na[sr][1], bfr[sc][2], r);
                // Di = Ur*Mi + Ui*Mr
                q = MFMA16(a[sr][0],  bfr[sc][2], q);
                q = MFMA16(a[sr][0],  bfr[sc][3], q);
                q = MFMA16(a[sr][1],  bfr[sc][2], q);
                q = MFMA16(a[sr][2],  bfr[sc][0], q);
                q = MFMA16(a[sr][2],  bfr[sc][1], q);
                q = MFMA16(a[sr][3],  bfr[sc][0], q);
                gr[sr][sc] = r; gi[sr][sc] = q;
            }
        }
        __syncthreads();
    }

    // epilogue: lane holds 4 consecutive k (rows) at one i (col) -> float4
    #pragma unroll
    for (int sr = 0; sr < 2; sr++)
        #pragma unroll
        for (int sc = 0; sc < 2; sc++) {
            const int k = kb0 + wr * 32 + sr * 16 + 4 * (lane >> 4);
            const int i = it  + wc * 32 + sc * 16 + (lane & 15);
            const size_t o = boff + (size_t)i * SI_ +
                (size_t)(k >> KL2_) * SKH_ + (size_t)(k & ((1 << KL2_) - 1));
            *(float4*)(dstR + o) = make_float4(gr[sr][sc][0], gr[sr][sc][1],
                                               gr[sr][sc][2], gr[sr][sc][3]);
            *(float4*)(dstI + o) = make_float4(gi[sr][sc][0], gi[sr][sc][1],
                                               gi[sr][sc][2], gi[sr][sc][3]);
        }
    #undef GADDR
}

// =====================================================================
// mix64_mfma (mode 2, d=64). R14 body (proven, no prefetch).
// =====================================================================
__global__ __launch_bounds__(256, 4)
void mix64_mfma_kernel(const float* __restrict__ srcR, const float* __restrict__ srcI,
                       const unsigned short* __restrict__ Mp,
                       float* __restrict__ dstR, float* __restrict__ dstI)
{
    const int kb0 = blockIdx.x << 6;   // 64-wide k tile
    const int b   = blockIdx.y;

    const int t    = threadIdx.x;
    const int lane = t & 63;
    const int wave = t >> 6;
    const int wr = wave & 1, wc = wave >> 1;   // wr: i half, wc: k half

    __shared__ unsigned short UP[4][2560];   // u^T planes [kcol][j 0..31], pitch 40
    __shared__ unsigned short MP[4][2560];   // M   planes [i   ][j 0..31], pitch 40

    const sh8 SGN = {(short)0x8000, (short)0x8000, (short)0x8000, (short)0x8000,
                     (short)0x8000, (short)0x8000, (short)0x8000, (short)0x8000};

    f32x4 gr[2][2], gi[2][2];     // [sr: i-sub][sc: k-sub]
    const f32x4 z4 = {0.f, 0.f, 0.f, 0.f};
    #pragma unroll
    for (int x = 0; x < 2; x++)
        #pragma unroll
        for (int y = 0; y < 2; y++) { gr[x][y] = z4; gi[x][y] = z4; }

    const size_t boff  = (size_t)b * SSIZE;
    const unsigned short* Mb = Mp + (size_t)b * 4 * 4096;    // 4 planes of 64*64
    const size_t koffb = (size_t)(kb0 & 127) * 64 + (size_t)(kb0 >> 7) * 8192;

    // staging maps
    const int mi  = t >> 2;        // i row for M
    const int mj8 = (t & 3) * 8;   // j octet for M
    const int ujq = t & 7;         // j quad: j0 = 4*ujq
    const int ukc = t >> 3;        // kcol 0..31 (+32 second item)

    const int frow = lane & 15;
    const int kg   = lane >> 4;

    for (int jt = 0; jt < 2; jt++) {
        const int jb = jt * 32;
        // ---- stage M: pure copy of pre-split planes
        {
            const int src = mi * 64 + jb + mj8;
            const int idx = mi * 40 + mj8;
            #pragma unroll
            for (int p = 0; p < 4; p++)
                *(uint4*)&MP[p][idx] = *(const uint4*)&Mb[p * 4096 + src];
        }
        // ---- stage u^T: 64 kcol x 32 j, j contiguous in memory
        #pragma unroll
        for (int m = 0; m < 2; m++) {
            const int kc = ukc + 32 * m;
            const size_t o = boff + koffb + (size_t)kc * 64 + jb + 4 * ujq;
            const float4 R = *(const float4*)(srcR + o);
            const float4 I = *(const float4*)(srcI + o);
            const int idx = kc * 40 + 4 * ujq;
            unsigned h0, l0, h1, l1;
            split2(R.x, R.y, h0, l0); split2(R.z, R.w, h1, l1);
            *(uint2*)&UP[0][idx] = make_uint2(h0, h1);
            *(uint2*)&UP[1][idx] = make_uint2(l0, l1);
            split2(I.x, I.y, h0, l0); split2(I.z, I.w, h1, l1);
            *(uint2*)&UP[2][idx] = make_uint2(h0, h1);
            *(uint2*)&UP[3][idx] = make_uint2(l0, l1);
        }
        __syncthreads();

        sh8 a[2][4], na[2][2], bfr[2][4];
        #pragma unroll
        for (int s = 0; s < 2; s++) {
            const int row = wr * 32 + s * 16 + frow;
            #pragma unroll
            for (int p = 0; p < 4; p++) a[s][p] = ldfrag40(&MP[p][0], row, kg);
            na[s][0] = a[s][2] ^ SGN;
            na[s][1] = a[s][3] ^ SGN;
        }
        #pragma unroll
        for (int s = 0; s < 2; s++) {
            const int row = wc * 32 + s * 16 + frow;
            #pragma unroll
            for (int p = 0; p < 4; p++) bfr[s][p] = ldfrag40(&UP[p][0], row, kg);
        }

        #pragma unroll
        for (int sr = 0; sr < 2; sr++) {
            #pragma unroll
            for (int sc = 0; sc < 2; sc++) {
                f32x4 r = gr[sr][sc], q = gi[sr][sc];
                r = MFMA16(a[sr][0],  bfr[sc][0], r);
                r = MFMA16(a[sr][0],  bfr[sc][1], r);
                r = MFMA16(a[sr][1],  bfr[sc][0], r);
                r = MFMA16(na[sr][0], bfr[sc][2], r);
                r = MFMA16(na[sr][0], bfr[sc][3], r);
                r = MFMA16(na[sr][1], bfr[sc][2], r);
                q = MFMA16(a[sr][0],  bfr[sc][2], q);
                q = MFMA16(a[sr][0],  bfr[sc][3], q);
                q = MFMA16(a[sr][1],  bfr[sc][2], q);
                q = MFMA16(a[sr][2],  bfr[sc][0], q);
                q = MFMA16(a[sr][2],  bfr[sc][1], q);
                q = MFMA16(a[sr][3],  bfr[sc][0], q);
                gr[sr][sc] = r; gi[sr][sc] = q;
            }
        }
        __syncthreads();
    }

    // epilogue: lane holds 4 consecutive i (rows) at one kcol (col) -> float4
    #pragma unroll
    for (int sr = 0; sr < 2; sr++)
        #pragma unroll
        for (int sc = 0; sc < 2; sc++) {
            const int i  = wr * 32 + sr * 16 + 4 * (lane >> 4);
            const int kc = wc * 32 + sc * 16 + (lane & 15);
            const size_t o = boff + koffb + (size_t)kc * 64 + i;
            *(float4*)(dstR + o) = make_float4(gr[sr][sc][0], gr[sr][sc][1],
                                               gr[sr][sc][2], gr[sr][sc][3]);
            *(float4*)(dstI + o) = make_float4(gi[sr][sc][0], gi[sr][sc][1],
                                               gi[sr][sc][2], gi[sr][sc][3]);
        }
}

extern "C" void kernel_launch(void* const* d_in, const int* in_sizes, int n_in,
                              void* d_out, int out_size, void* d_ws, size_t ws_size,
                              hipStream_t stream)
{
    const float* xr  = (const float*)d_in[0];
    const float* xi  = (const float*)d_in[1];
    const float* w0r = (const float*)d_in[2];
    const float* w0i = (const float*)d_in[3];
    const float* w1r = (const float*)d_in[4];
    const float* w1i = (const float*)d_in[5];
    const float* w2r = (const float*)d_in[6];
    const float* w2i = (const float*)d_in[7];
    const float* lt  = (const float*)d_in[8];

    float* outR = (float*)d_out;
    float* outI = outR + (size_t)BATCH * SSIZE;

    float*  wsR = (float*)d_ws;
    float*  wsI = wsR + (size_t)BATCH * SSIZE;
    float*  Gf  = wsI + (size_t)BATCH * SSIZE;
    // M planes: [b][4][d*d] ushort. d=128: 8*4*16384*2B = 1MB.
    unsigned short* Mp = (unsigned short*)(Gf + (size_t)BATCH * 128 * 128 * 2);

    // Partial slabs span the contiguous DEAD R+I pair (67.1 MB each):
    //  mode 0: outR..outI; mode 1: wsR..wsI; mode 2: outR..outI.
    // NS=64 (d=128): 8b*64*128*128*2*4B = 67.1MB = exact fit.
    //   grid 3*64*8 = 1536 = 6 blocks/CU, lb(256,4) => 4 resident.
    // NS=128 (d=64): 33.6MB. grid 128*8 = 1024 = 4/CU.

    // ---------------- mode 0: d=128, SI=8192, KL2=13
    gram_mfma_kernel<8192, 13, 0><<<dim3(3, 64, BATCH), 256, 0, stream>>>(xr, xi, outR, 128);
    reduce_kernel<64, 8192><<<dim3(256), 256, 0, stream>>>((const float4*)outR, (float4*)Gf);
    score_kernel<<<dim3(128, BATCH), 128, 0, stream>>>(Gf, w0r, w0i, lt, Mp, 128);
    mix128_mfma_kernel<8192, 13, 0><<<dim3(128, 2, BATCH), 256, 0, stream>>>(xr, xi, Mp, outR, outI);

    // ---------------- mode 1: d=128, SI=64, KL2=6, SKH=8192
    gram_mfma_kernel<64, 6, 8192><<<dim3(3, 64, BATCH), 256, 0, stream>>>(outR, outI, wsR, 128);
    reduce_kernel<64, 8192><<<dim3(256), 256, 0, stream>>>((const float4*)wsR, (float4*)Gf);
    score_kernel<<<dim3(128, BATCH), 128, 0, stream>>>(Gf, w1r, w1i, lt, Mp, 128);
    mix128_mfma_kernel<64, 6, 8192><<<dim3(128, 2, BATCH), 256, 0, stream>>>(outR, outI, Mp, wsR, wsI);

    // ---------------- mode 2: d=64, SI=1, k: (k&127)*64 + (k>>7)*8192
    gram64_mfma_kernel<<<dim3(128, BATCH), 256, 0, stream>>>(wsR, wsI, outR, 128);
    reduce_kernel<128, 2048><<<dim3(64), 256, 0, stream>>>((const float4*)outR, (float4*)Gf);
    score_kernel<<<dim3(64, BATCH), 64, 0, stream>>>(Gf, w2r, w2i, lt, Mp, 64);
    mix64_mfma_kernel<<<dim3(256, BATCH), 256, 0, stream>>>(wsR, wsI, Mp, outR, outI);
}

// Round 12
// 400.351 us; speedup vs baseline: 1.1475x; 1.0690x over previous
//
#include <hip/hip_runtime.h>
#include <hip/hip_bf16.h>
#include <math.h>

#define BATCH 8
#define SSIZE 1048576   // 128*128*64

// R18: (1) REVERT gram NS 64->32, lb back to (256,3) (R16 post-mortem:
// NS=64 doubled partial WRITE_SIZE 32.8->65.5MB, dur 46.2->50.4us --
// k-split lever is two-sided, NS=32 is measured optimum). (2) bf16 split
// via __float2bfloat16 HW cvt instead of bit-math RNE (identical RNE
// rounding, ~11->~4 VALU ops per value; m240: compiler handles scalar
// casts well). Everything else = R14 bodies (measured 422.0us).

typedef short sh8 __attribute__((ext_vector_type(8)));
typedef float f32x4 __attribute__((ext_vector_type(4)));

#define MFMA16(a, b, c) __builtin_amdgcn_mfma_f32_16x16x32_bf16((a), (b), (c), 0, 0, 0)

// f32 -> bf16 (RNE) via HW convert; bit-identical to manual RNE bit-math
__device__ __forceinline__ unsigned short bf_cvt(float x) {
    __hip_bfloat16 h = __float2bfloat16(x);
    return *reinterpret_cast<unsigned short*>(&h);
}

// split x into hi + lo bf16 (both RNE)
__device__ __forceinline__ void split1(float x, unsigned short &h, unsigned short &l) {
    h = bf_cvt(x);
    float hf = __uint_as_float((unsigned)h << 16);
    l = bf_cvt(x - hf);
}

// split two floats, pack hi pair / lo pair as u32 (a in low 16, b in high)
__device__ __forceinline__ void split2(float a, float b, unsigned &hh, unsigned &ll) {
    unsigned short ha = bf_cvt(a), hb = bf_cvt(b);
    hh = (unsigned)ha | ((unsigned)hb << 16);
    float ra = a - __uint_as_float((unsigned)ha << 16);
    float rb = b - __uint_as_float((unsigned)hb << 16);
    ll = (unsigned)bf_cvt(ra) | ((unsigned)bf_cvt(rb) << 16);
}

__device__ __forceinline__ float f4c(const float4 &v, int c) {
    return c == 0 ? v.x : c == 1 ? v.y : c == 2 ? v.z : v.w;
}

// fragment load, pitch-32 planes with XOR swizzle (gram kernels, proven)
__device__ __forceinline__ sh8 ldfrag(const unsigned short *pl, int row, int kg) {
    const int idx = (row * 32 + kg * 8) ^ ((row & 3) << 3);
    return *(const sh8 *)(pl + idx);
}

// fragment load, pitch-40 planes, no swizzle (mix kernels; bank-optimal)
__device__ __forceinline__ sh8 ldfrag40(const unsigned short *pl, int row, int kg) {
    return *(const sh8 *)(pl + row * 40 + kg * 8);
}

// ---------------- partial-slab reduce: out[b][r] = sum_s in[b][s][r] --------
template<int NS, int PERB>   // PERB in float4 units
__global__ __launch_bounds__(256)
void reduce_kernel(const float4* __restrict__ in, float4* __restrict__ out) {
    const int gid = blockIdx.x * blockDim.x + threadIdx.x;
    const int b = gid / PERB, r = gid - b * PERB;
    const float4* p = in + (size_t)b * NS * PERB + r;
    float4 a = p[0];
    #pragma unroll 8
    for (int s = 1; s < NS; s++) {
        const float4 v = p[(size_t)s * PERB];
        a.x += v.x; a.y += v.y; a.z += v.z; a.w += v.w;
    }
    out[gid] = a;
}

// =====================================================================
// gram_mfma (modes 0/1, d=128): G = u u^T, symmetric. R14 config:
// NS=32 (grid 3x32x8=768 = 3 blocks/CU), lb(256,3). Measured 46.2us.
// =====================================================================
template<int SI_, int KL2_, int SKH_>
__global__ __launch_bounds__(256, 3)
void gram_mfma_kernel(const float* __restrict__ srcR, const float* __restrict__ srcI,
                      float* __restrict__ Gp, int kPerBlock)
{
    const int tile = blockIdx.x;             // 0,1,2
    const int it = (tile == 2) ? 64 : 0;
    const int jt = (tile == 0) ? 0 : 64;
    const bool diag = (it == jt);
    const int b  = blockIdx.z;
    const int k0 = blockIdx.y * kPerBlock;

    const int t    = threadIdx.x;
    const int lane = t & 63;
    const int wave = t >> 6;          // 0..3
    const int wr = wave & 1, wc = wave >> 1;

    __shared__ unsigned short SA[4][2048];   // planes rH,rL,iH,iL  [64 rows][32 k]
    __shared__ unsigned short SB[4][2048];

    const sh8 SGN = {(short)0x8000, (short)0x8000, (short)0x8000, (short)0x8000,
                     (short)0x8000, (short)0x8000, (short)0x8000, (short)0x8000};

    f32x4 gr[2][2], gi[2][2];
    const f32x4 z4 = {0.f, 0.f, 0.f, 0.f};
    #pragma unroll
    for (int x = 0; x < 2; x++)
        #pragma unroll
        for (int y = 0; y < 2; y++) { gr[x][y] = z4; gi[x][y] = z4; }

    const size_t boff = (size_t)b * SSIZE;
    const int nT = kPerBlock >> 5;

    const int kq   = t & 7;
    const int row2 = t >> 3;

    const int frow = lane & 15;
    const int kg   = lane >> 4;

    #define GADDR(ii, k) (boff + (size_t)(ii) * SI_ + \
        (size_t)((k) >> KL2_) * SKH_ + (size_t)((k) & ((1 << KL2_) - 1)))

    for (int kt = 0; kt < nT; kt++) {
        const int kb = k0 + kt * 32;
        #pragma unroll
        for (int m = 0; m < 2; m++) {
            const int row = row2 + 32 * m;
            const int idx = (row * 32 + kq * 4) ^ ((row & 3) << 3);
            {
                const size_t off = GADDR(it + row, kb + kq * 4);
                const float4 R = *(const float4*)(srcR + off);
                const float4 I = *(const float4*)(srcI + off);
                ushort4 rh, rl, ih, il;
                split1(R.x, rh.x, rl.x); split1(R.y, rh.y, rl.y);
                split1(R.z, rh.z, rl.z); split1(R.w, rh.w, rl.w);
                split1(I.x, ih.x, il.x); split1(I.y, ih.y, il.y);
                split1(I.z, ih.z, il.z); split1(I.w, ih.w, il.w);
                *(ushort4*)&SA[0][idx] = rh;
                *(ushort4*)&SA[1][idx] = rl;
                *(ushort4*)&SA[2][idx] = ih;
                *(ushort4*)&SA[3][idx] = il;
            }
            if (!diag) {
                const size_t off = GADDR(jt + row, kb + kq * 4);
                const float4 R = *(const float4*)(srcR + off);
                const float4 I = *(const float4*)(srcI + off);
                ushort4 rh, rl, ih, il;
                split1(R.x, rh.x, rl.x); split1(R.y, rh.y, rl.y);
                split1(R.z, rh.z, rl.z); split1(R.w, rh.w, rl.w);
                split1(I.x, ih.x, il.x); split1(I.y, ih.y, il.y);
                split1(I.z, ih.z, il.z); split1(I.w, ih.w, il.w);
                *(ushort4*)&SB[0][idx] = rh;
                *(ushort4*)&SB[1][idx] = rl;
                *(ushort4*)&SB[2][idx] = ih;
                *(ushort4*)&SB[3][idx] = il;
            }
        }
        __syncthreads();

        unsigned short (*BP)[2048] = diag ? SA : SB;

        sh8 a[2][4], na[2][2], bfr[2][4];
        #pragma unroll
        for (int s = 0; s < 2; s++) {
            const int row = wr * 32 + s * 16 + frow;
            #pragma unroll
            for (int p = 0; p < 4; p++) a[s][p] = ldfrag(&SA[p][0], row, kg);
            na[s][0] = a[s][2] ^ SGN;
            na[s][1] = a[s][3] ^ SGN;
        }
        #pragma unroll
        for (int s = 0; s < 2; s++) {
            const int row = wc * 32 + s * 16 + frow;
            #pragma unroll
            for (int p = 0; p < 4; p++) bfr[s][p] = ldfrag(&BP[p][0], row, kg);
        }

        #pragma unroll
        for (int sr = 0; sr < 2; sr++) {
            #pragma unroll
            for (int sc = 0; sc < 2; sc++) {
                f32x4 r = gr[sr][sc], q = gi[sr][sc];
                r = MFMA16(a[sr][0],  bfr[sc][0], r);
                r = MFMA16(a[sr][0],  bfr[sc][1], r);
                r = MFMA16(a[sr][1],  bfr[sc][0], r);
                r = MFMA16(na[sr][0], bfr[sc][2], r);
                r = MFMA16(na[sr][0], bfr[sc][3], r);
                r = MFMA16(na[sr][1], bfr[sc][2], r);
                q = MFMA16(a[sr][0],  bfr[sc][2], q);
                q = MFMA16(a[sr][0],  bfr[sc][3], q);
                q = MFMA16(a[sr][1],  bfr[sc][2], q);
                q = MFMA16(a[sr][2],  bfr[sc][0], q);
                q = MFMA16(a[sr][2],  bfr[sc][1], q);
                q = MFMA16(a[sr][3],  bfr[sc][0], q);
                gr[sr][sc] = r; gi[sr][sc] = q;
            }
        }
        __syncthreads();
    }
    #undef GADDR

    float* Gb = Gp + ((size_t)b * gridDim.y + blockIdx.y) * (128 * 128 * 2);
    const int rb   = (lane >> 4) * 4;
    const int jcol = lane & 15;
    #pragma unroll
    for (int sr = 0; sr < 2; sr++)
        #pragma unroll
        for (int sc = 0; sc < 2; sc++)
            #pragma unroll
            for (int r = 0; r < 4; r++) {
                const int i = it + wr * 32 + sr * 16 + rb + r;
                const int j = jt + wc * 32 + sc * 16 + jcol;
                const float vr = gr[sr][sc][r], vi = gi[sr][sc][r];
                *(float2*)&Gb[(i * 128 + j) * 2] = make_float2(vr, vi);
                if (!diag)
                    *(float2*)&Gb[(j * 128 + i) * 2] = make_float2(vr, vi);
            }
}

// =====================================================================
// gram64_mfma (mode 2, d=64). R14 body (proven); lb(256,4).
// =====================================================================
__global__ __launch_bounds__(256, 4)
void gram64_mfma_kernel(const float* __restrict__ srcR, const float* __restrict__ srcI,
                        float* __restrict__ Gp, int kPerBlock)
{
    const int b  = blockIdx.y;
    const int k0 = blockIdx.x * kPerBlock;

    const int t    = threadIdx.x;
    const int lane = t & 63;
    const int wave = t >> 6;
    const int wr = wave & 1, wc = wave >> 1;

    __shared__ unsigned short SA[4][2048];   // planes [64 i][32 k]

    const sh8 SGN = {(short)0x8000, (short)0x8000, (short)0x8000, (short)0x8000,
                     (short)0x8000, (short)0x8000, (short)0x8000, (short)0x8000};

    f32x4 gr[2][2], gi[2][2];
    const f32x4 z4 = {0.f, 0.f, 0.f, 0.f};
    #pragma unroll
    for (int x = 0; x < 2; x++)
        #pragma unroll
        for (int y = 0; y < 2; y++) { gr[x][y] = z4; gi[x][y] = z4; }

    const size_t boff = (size_t)b * SSIZE;
    const int nT = kPerBlock >> 5;

    const int kp = t & 15;        // k = 2kp, 2kp+1 within tile
    const int i0 = (t >> 4) * 4;  // i quad

    const int frow = lane & 15;
    const int kg   = lane >> 4;

    for (int kt = 0; kt < nT; kt++) {
        const int kb = k0 + kt * 32;
        const int ke = kb + 2 * kp;
        const int ko = ke + 1;
        const size_t offE = boff + (size_t)(ke & 127) * 64 + (size_t)(ke >> 7) * 8192 + i0;
        const size_t offO = boff + (size_t)(ko & 127) * 64 + (size_t)(ko >> 7) * 8192 + i0;
        const float4 R0 = *(const float4*)(srcR + offE);
        const float4 I0 = *(const float4*)(srcI + offE);
        const float4 R1 = *(const float4*)(srcR + offO);
        const float4 I1 = *(const float4*)(srcI + offO);
        const int kw = 2 * kp;
        #pragma unroll
        for (int c = 0; c < 4; c++) {
            const int i   = i0 + c;
            const int idx = (i * 32 + kw) ^ ((i & 3) << 3);
            unsigned short h0, l0, h1, l1;
            split1(f4c(R0, c), h0, l0);
            split1(f4c(R1, c), h1, l1);
            *(ushort2*)&SA[0][idx] = make_ushort2(h0, h1);
            *(ushort2*)&SA[1][idx] = make_ushort2(l0, l1);
            split1(f4c(I0, c), h0, l0);
            split1(f4c(I1, c), h1, l1);
            *(ushort2*)&SA[2][idx] = make_ushort2(h0, h1);
            *(ushort2*)&SA[3][idx] = make_ushort2(l0, l1);
        }
        __syncthreads();

        sh8 a[2][4], na[2][2], bfr[2][4];
        #pragma unroll
        for (int s = 0; s < 2; s++) {
            const int row = wr * 32 + s * 16 + frow;
            #pragma unroll
            for (int p = 0; p < 4; p++) a[s][p] = ldfrag(&SA[p][0], row, kg);
            na[s][0] = a[s][2] ^ SGN;
            na[s][1] = a[s][3] ^ SGN;
        }
        #pragma unroll
        for (int s = 0; s < 2; s++) {
            const int row = wc * 32 + s * 16 + frow;
            #pragma unroll
            for (int p = 0; p < 4; p++) bfr[s][p] = ldfrag(&SA[p][0], row, kg);
        }

        #pragma unroll
        for (int sr = 0; sr < 2; sr++) {
            #pragma unroll
            for (int sc = 0; sc < 2; sc++) {
                f32x4 r = gr[sr][sc], q = gi[sr][sc];
                r = MFMA16(a[sr][0],  bfr[sc][0], r);
                r = MFMA16(a[sr][0],  bfr[sc][1], r);
                r = MFMA16(a[sr][1],  bfr[sc][0], r);
                r = MFMA16(na[sr][0], bfr[sc][2], r);
                r = MFMA16(na[sr][0], bfr[sc][3], r);
                r = MFMA16(na[sr][1], bfr[sc][2], r);
                q = MFMA16(a[sr][0],  bfr[sc][2], q);
                q = MFMA16(a[sr][0],  bfr[sc][3], q);
                q = MFMA16(a[sr][1],  bfr[sc][2], q);
                q = MFMA16(a[sr][2],  bfr[sc][0], q);
                q = MFMA16(a[sr][2],  bfr[sc][1], q);
                q = MFMA16(a[sr][3],  bfr[sc][0], q);
                gr[sr][sc] = r; gi[sr][sc] = q;
            }
        }
        __syncthreads();
    }

    float* Gb = Gp + ((size_t)b * gridDim.x + blockIdx.x) * (64 * 64 * 2);
    const int rb   = (lane >> 4) * 4;
    const int jcol = lane & 15;
    #pragma unroll
    for (int sr = 0; sr < 2; sr++)
        #pragma unroll
        for (int sc = 0; sc < 2; sc++)
            #pragma unroll
            for (int r = 0; r < 4; r++) {
                const int i = wr * 32 + sr * 16 + rb + r;
                const int j = wc * 32 + sc * 16 + jcol;
                *(float2*)&Gb[(i * 64 + j) * 2] = make_float2(gr[sr][sc][r], gi[sr][sc][r]);
            }
}

// ---------------- score/softmax/phase -> routing matrix M ----------------
// Writes M as 4 packed bf16 planes [b][p][d*d]: p=0 MrH, 1 MrL, 2 MiH, 3 MiL
__global__ __launch_bounds__(128)
void score_kernel(const float* __restrict__ G,
                  const float* __restrict__ Wre, const float* __restrict__ Wim,
                  const float* __restrict__ log_tau,
                  unsigned short* __restrict__ Mout, int d)
{
    const int b = blockIdx.y;
    const int i = blockIdx.x;
    const int j = threadIdx.x;

    const float2* Gb = (const float2*)G + (size_t)b * d * d;

    float sre = 0.f, sim = 0.f;
    for (int l = 0; l < d; l++) {
        float wr = Wre[i * d + l];
        float wi = Wim[i * d + l];
        float2 g = Gb[l * d + j];
        sre = fmaf(wr, g.x, sre);
        sre = fmaf(-wi, g.y, sre);
        sim = fmaf(wr, g.y, sim);
        sim = fmaf(wi, g.x, sim);
    }

    float mag = sqrtf(sre * sre + sim * sim);
    float tau = fmaxf(expf(log_tau[0]), 1e-8f);
    float scale = tau * sqrtf((float)SSIZE / (float)d);
    float mval = mag / scale;

    __shared__ float red[128];
    red[j] = mval;
    __syncthreads();
    for (int s = d >> 1; s > 0; s >>= 1) {
        if (j < s) red[j] = fmaxf(red[j], red[j + s]);
        __syncthreads();
    }
    float mx = red[0];
    __syncthreads();
    float e = expf(mval - mx);
    red[j] = e;
    __syncthreads();
    for (int s = d >> 1; s > 0; s >>= 1) {
        if (j < s) red[j] += red[j + s];
        __syncthreads();
    }
    float routing = e / red[0];

    float safe = fmaxf(mag, 1e-8f);
    float pre, pim;
    if (mag > 1e-8f) { pre = sre / safe; pim = sim / safe; }
    else             { pre = 1.f;       pim = 0.f; }

    const float mr = routing * pre;
    const float mi = routing * pim;
    const size_t dd = (size_t)d * d;
    unsigned short h, l;
    split1(mr, h, l);
    Mout[((size_t)b * 4 + 0) * dd + i * d + j] = h;
    Mout[((size_t)b * 4 + 1) * dd + i * d + j] = l;
    split1(mi, h, l);
    Mout[((size_t)b * 4 + 2) * dd + i * d + j] = h;
    Mout[((size_t)b * 4 + 3) * dd + i * d + j] = l;
}

// =====================================================================
// mix128_mfma (modes 0/1, d=128). R14 body (proven, no prefetch).
// =====================================================================
template<int SI_, int KL2_, int SKH_>
__global__ __launch_bounds__(256, 4)
void mix128_mfma_kernel(const float* __restrict__ srcR, const float* __restrict__ srcI,
                        const unsigned short* __restrict__ Mp,
                        float* __restrict__ dstR, float* __restrict__ dstI)
{
    const int kb0 = blockIdx.x << 6;   // 64-wide k tile
    const int it  = blockIdx.y << 6;   // 64-wide i tile
    const int b   = blockIdx.z;

    const int t    = threadIdx.x;
    const int lane = t & 63;
    const int wave = t >> 6;
    const int wr = wave & 1, wc = wave >> 1;   // wr: k half, wc: i half

    __shared__ unsigned short UP[4][2560];   // u^T planes [kcol 0..63][j 0..31], pitch 40
    __shared__ unsigned short MP[4][2560];   // M   planes [i    0..63][j 0..31], pitch 40

    const sh8 SGN = {(short)0x8000, (short)0x8000, (short)0x8000, (short)0x8000,
                     (short)0x8000, (short)0x8000, (short)0x8000, (short)0x8000};

    f32x4 gr[2][2], gi[2][2];     // [sr: k-sub][sc: i-sub]
    const f32x4 z4 = {0.f, 0.f, 0.f, 0.f};
    #pragma unroll
    for (int x = 0; x < 2; x++)
        #pragma unroll
        for (int y = 0; y < 2; y++) { gr[x][y] = z4; gi[x][y] = z4; }

    const size_t boff = (size_t)b * SSIZE;
    const unsigned short* Mb = Mp + (size_t)b * 4 * 16384;   // 4 planes of 128*128

    #define GADDR(jj, k) (boff + (size_t)(jj) * SI_ + \
        (size_t)((k) >> KL2_) * SKH_ + (size_t)((k) & ((1 << KL2_) - 1)))

    // staging maps
    const int ujp = t & 15;        // j pair: j0 = 2*ujp
    const int uq  = t >> 4;        // k quad: kc0 = 4*uq
    const int mi  = t >> 2;        // i row for M
    const int mj8 = (t & 3) * 8;   // j octet for M

    const int frow = lane & 15;
    const int kg   = lane >> 4;

    for (int jt = 0; jt < 4; jt++) {
        const int jb = jt * 32;
        // ---- stage M: pure copy of pre-split planes (16B loads/stores)
        {
            const int src = (it + mi) * 128 + jb + mj8;
            const int idx = mi * 40 + mj8;
            #pragma unroll
            for (int p = 0; p < 4; p++)
                *(uint4*)&MP[p][idx] = *(const uint4*)&Mb[p * 16384 + src];
        }
        // ---- stage u^T: 64 kcol x 32 j, uint stores (split in-kernel)
        {
            const int j0 = 2 * ujp;
            const size_t o0 = GADDR(jb + j0,     kb0 + 4 * uq);
            const size_t o1 = GADDR(jb + j0 + 1, kb0 + 4 * uq);
            const float4 R0 = *(const float4*)(srcR + o0);
            const float4 R1 = *(const float4*)(srcR + o1);
            const float4 I0 = *(const float4*)(srcI + o0);
            const float4 I1 = *(const float4*)(srcI + o1);
            #pragma unroll
            for (int c = 0; c < 4; c++) {
                const int kc  = 4 * uq + c;
                const int idx = kc * 40 + j0;
                unsigned hh, ll;
                split2(f4c(R0, c), f4c(R1, c), hh, ll);
                *(unsigned*)&UP[0][idx] = hh;
                *(unsigned*)&UP[1][idx] = ll;
                split2(f4c(I0, c), f4c(I1, c), hh, ll);
                *(unsigned*)&UP[2][idx] = hh;
                *(unsigned*)&UP[3][idx] = ll;
            }
        }
        __syncthreads();

        sh8 a[2][4], na[2][2], bfr[2][4];
        #pragma unroll
        for (int s = 0; s < 2; s++) {
            const int row = wr * 32 + s * 16 + frow;
            #pragma unroll
            for (int p = 0; p < 4; p++) a[s][p] = ldfrag40(&UP[p][0], row, kg);
            na[s][0] = a[s][2] ^ SGN;
            na[s][1] = a[s][3] ^ SGN;
        }
        #pragma unroll
        for (int s = 0; s < 2; s++) {
            const int row = wc * 32 + s * 16 + frow;
            #pragma unroll
            for (int p = 0; p < 4; p++) bfr[s][p] = ldfrag40(&MP[p][0], row, kg);
        }

        #pragma unroll
        for (int sr = 0; sr < 2; sr++) {
            #pragma unroll
            for (int sc = 0; sc < 2; sc++) {
                f32x4 r = gr[sr][sc], q = gi[sr][sc];
                // Dr = Ur*Mr - Ui*Mi (split HH+HL+LH)
                r = MFMA16(a[sr][0],  bfr[sc][0], r);
                r = MFMA16(a[sr][0],  bfr[sc][1], r);
                r = MFMA16(a[sr][1],  bfr[sc][0], r);
                r = MFMA16(na[sr][0], bfr[sc][2], r);
                r = MFMA16(na[sr][0], bfr[sc][3], r);
                r = MFMA16(na[sr][1], bfr[sc][2], r);
                // Di = Ur*Mi + Ui*Mr
                q = MFMA16(a[sr][0],  bfr[sc][2], q);
                q = MFMA16(a[sr][0],  bfr[sc][3], q);
                q = MFMA16(a[sr][1],  bfr[sc][2], q);
                q = MFMA16(a[sr][2],  bfr[sc][0], q);
                q = MFMA16(a[sr][2],  bfr[sc][1], q);
                q = MFMA16(a[sr][3],  bfr[sc][0], q);
                gr[sr][sc] = r; gi[sr][sc] = q;
            }
        }
        __syncthreads();
    }

    // epilogue: lane holds 4 consecutive k (rows) at one i (col) -> float4
    #pragma unroll
    for (int sr = 0; sr < 2; sr++)
        #pragma unroll
        for (int sc = 0; sc < 2; sc++) {
            const int k = kb0 + wr * 32 + sr * 16 + 4 * (lane >> 4);
            const int i = it  + wc * 32 + sc * 16 + (lane & 15);
            const size_t o = boff + (size_t)i * SI_ +
                (size_t)(k >> KL2_) * SKH_ + (size_t)(k & ((1 << KL2_) - 1));
            *(float4*)(dstR + o) = make_float4(gr[sr][sc][0], gr[sr][sc][1],
                                               gr[sr][sc][2], gr[sr][sc][3]);
            *(float4*)(dstI + o) = make_float4(gi[sr][sc][0], gi[sr][sc][1],
                                               gi[sr][sc][2], gi[sr][sc][3]);
        }
    #undef GADDR
}

// =====================================================================
// mix64_mfma (mode 2, d=64). R14 body (proven, no prefetch).
// =====================================================================
__global__ __launch_bounds__(256, 4)
void mix64_mfma_kernel(const float* __restrict__ srcR, const float* __restrict__ srcI,
                       const unsigned short* __restrict__ Mp,
                       float* __restrict__ dstR, float* __restrict__ dstI)
{
    const int kb0 = blockIdx.x << 6;   // 64-wide k tile
    const int b   = blockIdx.y;

    const int t    = threadIdx.x;
    const int lane = t & 63;
    const int wave = t >> 6;
    const int wr = wave & 1, wc = wave >> 1;   // wr: i half, wc: k half

    __shared__ unsigned short UP[4][2560];   // u^T planes [kcol][j 0..31], pitch 40
    __shared__ unsigned short MP[4][2560];   // M   planes [i   ][j 0..31], pitch 40

    const sh8 SGN = {(short)0x8000, (short)0x8000, (short)0x8000, (short)0x8000,
                     (short)0x8000, (short)0x8000, (short)0x8000, (short)0x8000};

    f32x4 gr[2][2], gi[2][2];     // [sr: i-sub][sc: k-sub]
    const f32x4 z4 = {0.f, 0.f, 0.f, 0.f};
    #pragma unroll
    for (int x = 0; x < 2; x++)
        #pragma unroll
        for (int y = 0; y < 2; y++) { gr[x][y] = z4; gi[x][y] = z4; }

    const size_t boff  = (size_t)b * SSIZE;
    const unsigned short* Mb = Mp + (size_t)b * 4 * 4096;    // 4 planes of 64*64
    const size_t koffb = (size_t)(kb0 & 127) * 64 + (size_t)(kb0 >> 7) * 8192;

    // staging maps
    const int mi  = t >> 2;        // i row for M
    const int mj8 = (t & 3) * 8;   // j octet for M
    const int ujq = t & 7;         // j quad: j0 = 4*ujq
    const int ukc = t >> 3;        // kcol 0..31 (+32 second item)

    const int frow = lane & 15;
    const int kg   = lane >> 4;

    for (int jt = 0; jt < 2; jt++) {
        const int jb = jt * 32;
        // ---- stage M: pure copy of pre-split planes
        {
            const int src = mi * 64 + jb + mj8;
            const int idx = mi * 40 + mj8;
            #pragma unroll
            for (int p = 0; p < 4; p++)
                *(uint4*)&MP[p][idx] = *(const uint4*)&Mb[p * 4096 + src];
        }
        // ---- stage u^T: 64 kcol x 32 j, j contiguous in memory
        #pragma unroll
        for (int m = 0; m < 2; m++) {
            const int kc = ukc + 32 * m;
            const size_t o = boff + koffb + (size_t)kc * 64 + jb + 4 * ujq;
            const float4 R = *(const float4*)(srcR + o);
            const float4 I = *(const float4*)(srcI + o);
            const int idx = kc * 40 + 4 * ujq;
            unsigned h0, l0, h1, l1;
            split2(R.x, R.y, h0, l0); split2(R.z, R.w, h1, l1);
            *(uint2*)&UP[0][idx] = make_uint2(h0, h1);
            *(uint2*)&UP[1][idx] = make_uint2(l0, l1);
            split2(I.x, I.y, h0, l0); split2(I.z, I.w, h1, l1);
            *(uint2*)&UP[2][idx] = make_uint2(h0, h1);
            *(uint2*)&UP[3][idx] = make_uint2(l0, l1);
        }
        __syncthreads();

        sh8 a[2][4], na[2][2], bfr[2][4];
        #pragma unroll
        for (int s = 0; s < 2; s++) {
            const int row = wr * 32 + s * 16 + frow;
            #pragma unroll
            for (int p = 0; p < 4; p++) a[s][p] = ldfrag40(&MP[p][0], row, kg);
            na[s][0] = a[s][2] ^ SGN;
            na[s][1] = a[s][3] ^ SGN;
        }
        #pragma unroll
        for (int s = 0; s < 2; s++) {
            const int row = wc * 32 + s * 16 + frow;
            #pragma unroll
            for (int p = 0; p < 4; p++) bfr[s][p] = ldfrag40(&UP[p][0], row, kg);
        }

        #pragma unroll
        for (int sr = 0; sr < 2; sr++) {
            #pragma unroll
            for (int sc = 0; sc < 2; sc++) {
                f32x4 r = gr[sr][sc], q = gi[sr][sc];
                r = MFMA16(a[sr][0],  bfr[sc][0], r);
                r = MFMA16(a[sr][0],  bfr[sc][1], r);
                r = MFMA16(a[sr][1],  bfr[sc][0], r);
                r = MFMA16(na[sr][0], bfr[sc][2], r);
                r = MFMA16(na[sr][0], bfr[sc][3], r);
                r = MFMA16(na[sr][1], bfr[sc][2], r);
                q = MFMA16(a[sr][0],  bfr[sc][2], q);
                q = MFMA16(a[sr][0],  bfr[sc][3], q);
                q = MFMA16(a[sr][1],  bfr[sc][2], q);
                q = MFMA16(a[sr][2],  bfr[sc][0], q);
                q = MFMA16(a[sr][2],  bfr[sc][1], q);
                q = MFMA16(a[sr][3],  bfr[sc][0], q);
                gr[sr][sc] = r; gi[sr][sc] = q;
            }
        }
        __syncthreads();
    }

    // epilogue: lane holds 4 consecutive i (rows) at one kcol (col) -> float4
    #pragma unroll
    for (int sr = 0; sr < 2; sr++)
        #pragma unroll
        for (int sc = 0; sc < 2; sc++) {
            const int i  = wr * 32 + sr * 16 + 4 * (lane >> 4);
            const int kc = wc * 32 + sc * 16 + (lane & 15);
            const size_t o = boff + koffb + (size_t)kc * 64 + i;
            *(float4*)(dstR + o) = make_float4(gr[sr][sc][0], gr[sr][sc][1],
                                               gr[sr][sc][2], gr[sr][sc][3]);
            *(float4*)(dstI + o) = make_float4(gi[sr][sc][0], gi[sr][sc][1],
                                               gi[sr][sc][2], gi[sr][sc][3]);
        }
}

extern "C" void kernel_launch(void* const* d_in, const int* in_sizes, int n_in,
                              void* d_out, int out_size, void* d_ws, size_t ws_size,
                              hipStream_t stream)
{
    const float* xr  = (const float*)d_in[0];
    const float* xi  = (const float*)d_in[1];
    const float* w0r = (const float*)d_in[2];
    const float* w0i = (const float*)d_in[3];
    const float* w1r = (const float*)d_in[4];
    const float* w1i = (const float*)d_in[5];
    const float* w2r = (const float*)d_in[6];
    const float* w2i = (const float*)d_in[7];
    const float* lt  = (const float*)d_in[8];

    float* outR = (float*)d_out;
    float* outI = outR + (size_t)BATCH * SSIZE;

    float*  wsR = (float*)d_ws;
    float*  wsI = wsR + (size_t)BATCH * SSIZE;
    float*  Gf  = wsI + (size_t)BATCH * SSIZE;
    // M planes: [b][4][d*d] ushort. d=128: 8*4*16384*2B = 1MB.
    unsigned short* Mp = (unsigned short*)(Gf + (size_t)BATCH * 128 * 128 * 2);

    // Partial slabs span the contiguous DEAD R+I pair:
    //  mode 0: outR..outI; mode 1: wsR..wsI; mode 2: outR..outI.
    // NS=32 (d=128): 33.6MB < 64MB. grid 3*32*8 = 768 = 3/CU (measured opt).
    // NS=128 (d=64): 33.6MB. grid 128*8 = 1024 = 4/CU.

    // ---------------- mode 0: d=128, SI=8192, KL2=13
    gram_mfma_kernel<8192, 13, 0><<<dim3(3, 32, BATCH), 256, 0, stream>>>(xr, xi, outR, 256);
    reduce_kernel<32, 8192><<<dim3(256), 256, 0, stream>>>((const float4*)outR, (float4*)Gf);
    score_kernel<<<dim3(128, BATCH), 128, 0, stream>>>(Gf, w0r, w0i, lt, Mp, 128);
    mix128_mfma_kernel<8192, 13, 0><<<dim3(128, 2, BATCH), 256, 0, stream>>>(xr, xi, Mp, outR, outI);

    // ---------------- mode 1: d=128, SI=64, KL2=6, SKH=8192
    gram_mfma_kernel<64, 6, 8192><<<dim3(3, 32, BATCH), 256, 0, stream>>>(outR, outI, wsR, 256);
    reduce_kernel<32, 8192><<<dim3(256), 256, 0, stream>>>((const float4*)wsR, (float4*)Gf);
    score_kernel<<<dim3(128, BATCH), 128, 0, stream>>>(Gf, w1r, w1i, lt, Mp, 128);
    mix128_mfma_kernel<64, 6, 8192><<<dim3(128, 2, BATCH), 256, 0, stream>>>(outR, outI, Mp, wsR, wsI);

    // ---------------- mode 2: d=64, SI=1, k: (k&127)*64 + (k>>7)*8192
    gram64_mfma_kernel<<<dim3(128, BATCH), 256, 0, stream>>>(wsR, wsI, outR, 128);
    reduce_kernel<128, 2048><<<dim3(64), 256, 0, stream>>>((const float4*)outR, (float4*)Gf);
    score_kernel<<<dim3(64, BATCH), 64, 0, stream>>>(Gf, w2r, w2i, lt, Mp, 64);
    mix64_mfma_kernel<<<dim3(256, BATCH), 256, 0, stream>>>(wsR, wsI, Mp, outR, outI);
}